// Round 3
// baseline (520.449 us; speedup 1.0000x reference)
//
#include <hip/hip_runtime.h>
#include <hip/hip_bf16.h>

#define NNODE 100000
#define NEDGE 1600000
#define SBLK 1024
#define NBLK ((NNODE + SBLK - 1) / SBLK)   // 98
#define NBUCK ((NNODE + 63) >> 6)          // 1563 buckets of 64 dst-nodes

typedef __attribute__((ext_vector_type(8))) short bf16x8;
typedef __attribute__((ext_vector_type(4))) float f32x4;

__device__ __forceinline__ unsigned short f2bf(float f){
  unsigned u = __float_as_uint(f);
  u += 0x7fffu + ((u >> 16) & 1u);
  return (unsigned short)(u >> 16);
}
__device__ __forceinline__ unsigned pk2(float a, float b){
  return (unsigned)f2bf(a) | ((unsigned)f2bf(b) << 16);
}
__device__ __forceinline__ float bflo(unsigned v){ return __uint_as_float(v << 16); }
__device__ __forceinline__ float bfhi(unsigned v){ return __uint_as_float(v & 0xffff0000u); }

// ---------------- CSR build ----------------
__global__ void k_count(const int* __restrict__ dst, unsigned* __restrict__ cnt){
  int i = blockIdx.x * 256 + threadIdx.x;
  if (i < NEDGE) atomicAdd(&cnt[dst[i]], 1u);
}

// two-level parallel scan: (1) per-block sums
__global__ __launch_bounds__(1024) void k_blocksum(const unsigned* __restrict__ cnt,
                                                   unsigned* __restrict__ bsum){
  int i = blockIdx.x * SBLK + threadIdx.x;
  unsigned v = (i < NNODE) ? cnt[i] : 0u;
  #pragma unroll
  for (int off = 32; off; off >>= 1) v += __shfl_down(v, off, 64);
  __shared__ unsigned wsum[16];
  int lane = threadIdx.x & 63, wv = threadIdx.x >> 6;
  if (lane == 0) wsum[wv] = v;
  __syncthreads();
  if (wv == 0){
    unsigned t = (lane < 16) ? wsum[lane] : 0u;
    #pragma unroll
    for (int off = 8; off; off >>= 1) t += __shfl_down(t, off, 64);
    if (lane == 0) bsum[blockIdx.x] = t;
  }
}

// (2) exclusive-scan the 98 block sums in place
__global__ __launch_bounds__(128) void k_scanbsum(unsigned* __restrict__ bsum){
  __shared__ unsigned buf[128];
  int tid = threadIdx.x;
  unsigned v = (tid < NBLK) ? bsum[tid] : 0u;
  buf[tid] = v;
  __syncthreads();
  #pragma unroll
  for (int off = 1; off < 128; off <<= 1){
    unsigned t = (tid >= off) ? buf[tid - off] : 0u;
    __syncthreads();
    buf[tid] += t;
    __syncthreads();
  }
  if (tid < NBLK) bsum[tid] = buf[tid] - v;   // exclusive
}

// (3) per-block scan + apply offsets -> rowptr, cursor
__global__ __launch_bounds__(1024) void k_scanapply(const unsigned* __restrict__ cnt,
                                                    const unsigned* __restrict__ bsum,
                                                    unsigned* __restrict__ rowptr,
                                                    unsigned* __restrict__ cursor){
  int i = blockIdx.x * SBLK + threadIdx.x;
  unsigned v = (i < NNODE) ? cnt[i] : 0u;
  int lane = threadIdx.x & 63, wv = threadIdx.x >> 6;
  unsigned s = v;
  #pragma unroll
  for (int off = 1; off < 64; off <<= 1){
    unsigned t = __shfl_up(s, off, 64);
    if (lane >= off) s += t;
  }
  __shared__ unsigned wsum[16];
  if (lane == 63) wsum[wv] = s;
  __syncthreads();
  unsigned woff = 0;
  for (int w = 0; w < wv; ++w) woff += wsum[w];
  if (i < NNODE){
    unsigned excl = bsum[blockIdx.x] + woff + s - v;
    rowptr[i] = excl;
    cursor[i] = excl;
  }
  if (blockIdx.x == 0 && threadIdx.x == 0) rowptr[NNODE] = NEDGE;
}

// bucket cursors: one cache line (16 u32) per bucket to avoid atomic line-serialization
__global__ void k_binit(const unsigned* __restrict__ rowptr, unsigned* __restrict__ bcursor){
  int b = blockIdx.x * 256 + threadIdx.x;
  if (b < NBUCK) bcursor[b * 16] = rowptr[b << 6];
}

// bin edges into 64-node buckets; packed entry = (src<<6) | (dst&63)
__global__ void k_binscatter(const int* __restrict__ src, const int* __restrict__ dst,
                             unsigned* __restrict__ bcursor, unsigned* __restrict__ pairs){
  int i = blockIdx.x * 256 + threadIdx.x;
  if (i < NEDGE){
    int s = src[i], d = dst[i];
    unsigned p = atomicAdd(&bcursor[(d >> 6) * 16], 1u);
    pairs[p] = ((unsigned)s << 6) | (unsigned)(d & 63);
  }
}

// per-bucket final placement: reads and writes stay inside the bucket's window
__global__ __launch_bounds__(256) void k_bucketsort(const unsigned* __restrict__ rowptr,
                                                    unsigned* __restrict__ cursor,
                                                    const unsigned* __restrict__ pairs,
                                                    unsigned* __restrict__ col){
  int b = blockIdx.x;
  int nb0 = b << 6;
  int nb1 = nb0 + 64; if (nb1 > NNODE) nb1 = NNODE;
  unsigned e0 = rowptr[nb0], e1 = rowptr[nb1];
  for (unsigned j = e0 + threadIdx.x; j < e1; j += 256){
    unsigned e = pairs[j];
    unsigned d = (unsigned)nb0 + (e & 63u);
    unsigned p = atomicAdd(&cursor[d], 1u);
    col[p] = e >> 6;
  }
}

// ---------------- conversions ----------------
__global__ void k_xcvt(const float* __restrict__ x, unsigned* __restrict__ A1u){
  int i = blockIdx.x * 256 + threadIdx.x;   // over N*32 float4s
  if (i >= NNODE * 32) return;
  float4 v = ((const float4*)x)[i];
  int e = i * 4;
  int row = e >> 7, c = e & 127;
  unsigned* d = A1u + (size_t)row * 128 + 64 + (c >> 1);
  d[0] = pk2(v.x, v.y);
  d[1] = pk2(v.z, v.w);
}

__global__ void k_wcvt1(const float* __restrict__ W1l, const float* __restrict__ W1r,
                        unsigned short* __restrict__ Bwt1){
  int i = blockIdx.x * 256 + threadIdx.x;
  if (i >= 256 * 256) return;
  int n = i >> 8, k = i & 255;
  float v = (k < 128) ? W1l[n * 128 + k] : W1r[n * 128 + (k - 128)];
  Bwt1[i] = f2bf(v);
}

__global__ void k_wcvt2(const float* __restrict__ W2l, const float* __restrict__ W2r,
                        unsigned short* __restrict__ Bwt2){
  int i = blockIdx.x * 256 + threadIdx.x;
  if (i >= 128 * 256) return;
  int n = i >> 8, k = i & 255;
  float v = (n < 64) ? W2l[n * 256 + k] : W2r[(n - 64) * 256 + k];
  Bwt2[i] = f2bf(v);
}

// ---------------- layer-1 aggregation ----------------
__global__ __launch_bounds__(256) void k_agg1(const unsigned* __restrict__ rowptr,
                                              const unsigned* __restrict__ col,
                                              unsigned* __restrict__ A1u){
  int gw = (blockIdx.x * 256 + threadIdx.x) >> 6;
  int lane = threadIdx.x & 63;
  if (gw >= NNODE) return;
  unsigned s0 = rowptr[gw], s1 = rowptr[gw + 1];
  float ax = 0.f, ay = 0.f;
  unsigned j = s0;
  for (; j + 1 < s1; j += 2){
    unsigned sa = col[j], sb = col[j + 1];
    unsigned va = A1u[(size_t)sa * 128 + 64 + lane];
    unsigned vb = A1u[(size_t)sb * 128 + 64 + lane];
    ax += bflo(va) + bflo(vb);
    ay += bfhi(va) + bfhi(vb);
  }
  if (j < s1){
    unsigned v = A1u[(size_t)col[j] * 128 + 64 + lane];
    ax += bflo(v); ay += bfhi(v);
  }
  float inv = 1.f / fmaxf((float)(s1 - s0), 1.f);
  A1u[(size_t)gw * 128 + lane] = pk2(ax * inv, ay * inv);
}

// ---------------- MFMA GEMM ----------------
template<int BN, bool RELU, bool BIAS>
__global__ __launch_bounds__(256) void k_gemm(const unsigned short* __restrict__ A,
                                              const unsigned short* __restrict__ B,
                                              const float* __restrict__ bias,
                                              unsigned short* __restrict__ C,
                                              int nrows){
  constexpr int NF = BN / 64;
  __shared__ unsigned short a_t[64 * 64];
  __shared__ unsigned short b_t[BN * 64];
  const int tid = threadIdx.x, wave = tid >> 6, lane = tid & 63;
  const int row0 = blockIdx.x * 64;
  char* ab = (char*)a_t;
  char* bb = (char*)b_t;

  f32x4 acc[4][NF];
  #pragma unroll
  for (int m = 0; m < 4; ++m)
    #pragma unroll
    for (int n = 0; n < NF; ++n)
      acc[m][n] = (f32x4){0.f, 0.f, 0.f, 0.f};

  for (int kt = 0; kt < 4; ++kt){
    {
      int r = tid >> 2;
      int gr = row0 + r; if (gr > nrows - 1) gr = nrows - 1;
      const uint4* s4 = (const uint4*)(A + (size_t)gr * 256 + kt * 64);
      int c0 = (tid & 3) * 2;
      uint4 v0 = s4[c0], v1 = s4[c0 + 1];
      *(uint4*)(ab + r * 128 + ((c0 * 16) ^ ((r & 7) << 4))) = v0;
      *(uint4*)(ab + r * 128 + (((c0 + 1) * 16) ^ ((r & 7) << 4))) = v1;
    }
    {
      constexpr int CPT = BN / 32;
      #pragma unroll
      for (int c = 0; c < CPT; ++c){
        int gc = tid * CPT + c;
        int n = gc >> 3, ck = gc & 7;
        uint4 v = ((const uint4*)(B + (size_t)n * 256 + kt * 64))[ck];
        *(uint4*)(bb + n * 128 + ((ck * 16) ^ ((n & 7) << 4))) = v;
      }
    }
    __syncthreads();
    #pragma unroll
    for (int kk = 0; kk < 2; ++kk){
      int k2 = (kk * 32 + ((lane >> 4) * 8)) * 2;
      bf16x8 af[4];
      #pragma unroll
      for (int m = 0; m < 4; ++m){
        int rr = m * 16 + (lane & 15);
        af[m] = *(const bf16x8*)(ab + rr * 128 + (k2 ^ ((rr & 7) << 4)));
      }
      #pragma unroll
      for (int n = 0; n < NF; ++n){
        int cc = wave * (16 * NF) + n * 16 + (lane & 15);
        bf16x8 bfv = *(const bf16x8*)(bb + cc * 128 + (k2 ^ ((cc & 7) << 4)));
        #pragma unroll
        for (int m = 0; m < 4; ++m)
          acc[m][n] = __builtin_amdgcn_mfma_f32_16x16x32_bf16(af[m], bfv, acc[m][n], 0, 0, 0);
      }
    }
    __syncthreads();
  }
  #pragma unroll
  for (int m = 0; m < 4; ++m){
    int rbase = row0 + m * 16 + ((lane >> 4) << 2);
    #pragma unroll
    for (int r = 0; r < 4; ++r){
      if (rbase + r < nrows){
        #pragma unroll
        for (int n = 0; n < NF; ++n){
          int cc = wave * (16 * NF) + n * 16 + (lane & 15);
          float v = acc[m][n][r];
          if (BIAS) v += bias[cc];
          if (RELU) v = fmaxf(v, 0.f);
          C[(size_t)(rbase + r) * BN + cc] = f2bf(v);
        }
      }
    }
  }
}

// ---------------- layer-2 aggregation + residual + bias ----------------
__global__ __launch_bounds__(256) void k_agg2(const unsigned* __restrict__ rowptr,
                                              const unsigned* __restrict__ col,
                                              const unsigned short* __restrict__ zr,
                                              const float* __restrict__ b2,
                                              float* __restrict__ out){
  int t = blockIdx.x * 256 + threadIdx.x;
  int node = t >> 4, gl = t & 15;
  if (node >= NNODE) return;
  unsigned s0 = rowptr[node], s1 = rowptr[node + 1];
  float a0 = 0.f, a1 = 0.f, a2 = 0.f, a3 = 0.f;
  unsigned j = s0;
  for (; j + 1 < s1; j += 2){
    unsigned sa = col[j], sb = col[j + 1];
    uint2 va = *(const uint2*)(zr + (size_t)sa * 128 + gl * 4);
    uint2 vb = *(const uint2*)(zr + (size_t)sb * 128 + gl * 4);
    a0 += bflo(va.x) + bflo(vb.x); a1 += bfhi(va.x) + bfhi(vb.x);
    a2 += bflo(va.y) + bflo(vb.y); a3 += bfhi(va.y) + bfhi(vb.y);
  }
  if (j < s1){
    uint2 v = *(const uint2*)(zr + (size_t)col[j] * 128 + gl * 4);
    a0 += bflo(v.x); a1 += bfhi(v.x); a2 += bflo(v.y); a3 += bfhi(v.y);
  }
  float inv = 1.f / fmaxf((float)(s1 - s0), 1.f);
  uint2 rv = *(const uint2*)(zr + (size_t)node * 128 + 64 + gl * 4);
  float4 res;
  res.x = a0 * inv + bflo(rv.x) + b2[gl * 4 + 0];
  res.y = a1 * inv + bfhi(rv.x) + b2[gl * 4 + 1];
  res.z = a2 * inv + bflo(rv.y) + b2[gl * 4 + 2];
  res.w = a3 * inv + bfhi(rv.y) + b2[gl * 4 + 3];
  ((float4*)out)[(size_t)node * 16 + gl] = res;
}

extern "C" void kernel_launch(void* const* d_in, const int* in_sizes, int n_in,
                              void* d_out, int out_size, void* d_ws, size_t ws_size,
                              hipStream_t stream) {
  const float* x   = (const float*)d_in[0];
  const int*   ei  = (const int*)d_in[1];
  const float* W1l = (const float*)d_in[2];
  const float* b1  = (const float*)d_in[3];
  const float* W1r = (const float*)d_in[4];
  const float* W2l = (const float*)d_in[5];
  const float* b2  = (const float*)d_in[6];
  const float* W2r = (const float*)d_in[7];
  float* out = (float*)d_out;

  char* ws = (char*)d_ws;
  size_t off = 0;
  auto alloc = [&](size_t bytes) -> void* {
    void* p = ws + off;
    off = (off + bytes + 255) & ~(size_t)255;
    return p;
  };
  unsigned* cnt     = (unsigned*)alloc((size_t)NNODE * 4);
  unsigned* rowptr  = (unsigned*)alloc((size_t)(NNODE + 1) * 4);
  unsigned* cursor  = (unsigned*)alloc((size_t)NNODE * 4);
  unsigned* col     = (unsigned*)alloc((size_t)NEDGE * 4);
  unsigned* pairs   = (unsigned*)alloc((size_t)NEDGE * 4);
  unsigned* bcursor = (unsigned*)alloc((size_t)NBUCK * 16 * 4);
  unsigned* bsum    = (unsigned*)alloc((size_t)NBLK * 4);
  unsigned short* A1   = (unsigned short*)alloc((size_t)NNODE * 256 * 2);
  unsigned short* h    = (unsigned short*)alloc((size_t)NNODE * 256 * 2);
  unsigned short* zr   = (unsigned short*)alloc((size_t)NNODE * 128 * 2);
  unsigned short* Bwt1 = (unsigned short*)alloc(256 * 256 * 2);
  unsigned short* Bwt2 = (unsigned short*)alloc(128 * 256 * 2);

  const int* srcv = ei;
  const int* dstv = ei + NEDGE;

  hipMemsetAsync(cnt, 0, (size_t)NNODE * 4, stream);

  k_count<<<(NEDGE + 255) / 256, 256, 0, stream>>>(dstv, cnt);
  k_blocksum<<<NBLK, 1024, 0, stream>>>(cnt, bsum);
  k_scanbsum<<<1, 128, 0, stream>>>(bsum);
  k_scanapply<<<NBLK, 1024, 0, stream>>>(cnt, bsum, rowptr, cursor);
  k_binit<<<(NBUCK + 255) / 256, 256, 0, stream>>>(rowptr, bcursor);
  k_binscatter<<<(NEDGE + 255) / 256, 256, 0, stream>>>(srcv, dstv, bcursor, pairs);
  k_bucketsort<<<NBUCK, 256, 0, stream>>>(rowptr, cursor, pairs, col);

  k_xcvt<<<(NNODE * 32 + 255) / 256, 256, 0, stream>>>(x, (unsigned*)A1);
  k_wcvt1<<<256, 256, 0, stream>>>(W1l, W1r, Bwt1);
  k_wcvt2<<<128, 256, 0, stream>>>(W2l, W2r, Bwt2);

  k_agg1<<<(NNODE + 3) / 4, 256, 0, stream>>>(rowptr, col, (unsigned*)A1);

  int gblocks = (NNODE + 63) / 64;
  k_gemm<256, true,  true ><<<gblocks, 256, 0, stream>>>(A1, Bwt1, b1, h, NNODE);
  k_gemm<128, false, false><<<gblocks, 256, 0, stream>>>(h,  Bwt2, nullptr, zr, NNODE);

  k_agg2<<<(NNODE * 16 + 255) / 256, 256, 0, stream>>>(rowptr, col, zr, b2, out);
}

// Round 5
// 330.770 us; speedup vs baseline: 1.5734x; 1.5734x over previous
//
#include <hip/hip_runtime.h>
#include <hip/hip_bf16.h>

#define NNODE 100000
#define NEDGE 1600000
#define NBBLK 512
#define CHUNK (NEDGE / NBBLK)              // 3125 edges per binning block
#define NB2 ((NNODE + 1023) >> 10)         // 98 buckets of 1024 dst-nodes

typedef __attribute__((ext_vector_type(8))) short bf16x8;
typedef __attribute__((ext_vector_type(4))) float f32x4;

__device__ __forceinline__ unsigned short f2bf(float f){
  unsigned u = __float_as_uint(f);
  u += 0x7fffu + ((u >> 16) & 1u);
  return (unsigned short)(u >> 16);
}
__device__ __forceinline__ unsigned pk2(float a, float b){
  return (unsigned)f2bf(a) | ((unsigned)f2bf(b) << 16);
}
__device__ __forceinline__ float bflo(unsigned v){ return __uint_as_float(v << 16); }
__device__ __forceinline__ float bfhi(unsigned v){ return __uint_as_float(v & 0xffff0000u); }

// ---------------- CSR build: deterministic 2-pass binning ----------------
// Pass A: per-chunk histogram over 98 coarse buckets (dst >> 10)
__global__ __launch_bounds__(256) void k_hist(const int* __restrict__ dst,
                                              unsigned* __restrict__ gh){
  __shared__ unsigned h[NB2];
  for (int t = threadIdx.x; t < NB2; t += 256) h[t] = 0;
  __syncthreads();
  int base = blockIdx.x * CHUNK;
  for (int j = threadIdx.x; j < CHUNK; j += 256)
    atomicAdd(&h[dst[base + j] >> 10], 1u);
  __syncthreads();
  for (int t = threadIdx.x; t < NB2; t += 256) gh[blockIdx.x * NB2 + t] = h[t];
}

// Pass B1: per-bucket scan across the 512 chunks -> local exclusive prefix + totals
__global__ __launch_bounds__(512) void k_scan512(const unsigned* __restrict__ gh,
                                                 unsigned* __restrict__ gbase,
                                                 unsigned* __restrict__ btot){
  int b = blockIdx.x, t = threadIdx.x;
  int lane = t & 63, wv = t >> 6;
  unsigned v = gh[t * NB2 + b];
  unsigned s = v;
  #pragma unroll
  for (int off = 1; off < 64; off <<= 1){
    unsigned u = __shfl_up(s, off, 64);
    if (lane >= off) s += u;
  }
  __shared__ unsigned wsum[8];
  if (lane == 63) wsum[wv] = s;
  __syncthreads();
  unsigned woff = 0;
  for (int w = 0; w < wv; ++w) woff += wsum[w];
  gbase[t * NB2 + b] = woff + s - v;          // local exclusive prefix
  if (t == 511) btot[b] = woff + s;           // bucket total
}

// Pass B2: exclusive-scan the 98 bucket totals -> bbase[0..98]
__global__ __launch_bounds__(128) void k_scanb(const unsigned* __restrict__ btot,
                                               unsigned* __restrict__ bbase,
                                               unsigned* __restrict__ rowptr){
  __shared__ unsigned buf[128];
  int tid = threadIdx.x;
  unsigned v = (tid < NB2) ? btot[tid] : 0u;
  buf[tid] = v;
  __syncthreads();
  #pragma unroll
  for (int off = 1; off < 128; off <<= 1){
    unsigned t = (tid >= off) ? buf[tid - off] : 0u;
    __syncthreads();
    buf[tid] += t;
    __syncthreads();
  }
  if (tid < NB2) bbase[tid] = buf[tid] - v;
  if (tid == 0){ bbase[NB2] = NEDGE; rowptr[NNODE] = NEDGE; }
}

// Pass C: place edges into bucket-contiguous `pairs`; writes are ~32-word runs
__global__ __launch_bounds__(256) void k_binscat(const int* __restrict__ src,
                                                 const int* __restrict__ dst,
                                                 const unsigned* __restrict__ gbase,
                                                 const unsigned* __restrict__ bbase,
                                                 unsigned* __restrict__ pairs){
  __shared__ unsigned cur[NB2];
  for (int t = threadIdx.x; t < NB2; t += 256)
    cur[t] = bbase[t] + gbase[blockIdx.x * NB2 + t];
  __syncthreads();
  int base = blockIdx.x * CHUNK;
  for (int j = threadIdx.x; j < CHUNK; j += 256){
    int s = src[base + j], d = dst[base + j];
    unsigned p = atomicAdd(&cur[d >> 10], 1u);
    pairs[p] = ((unsigned)s << 10) | (unsigned)(d & 1023);
  }
}

// Pass D: per-bucket node histogram + scan -> rowptr (contiguous) + col placement (LDS cursors)
__global__ __launch_bounds__(1024) void k_buildcsr(const unsigned* __restrict__ bbase,
                                                   const unsigned* __restrict__ pairs,
                                                   unsigned* __restrict__ rowptr,
                                                   unsigned* __restrict__ col){
  __shared__ unsigned hist[1024];
  __shared__ unsigned wsum[16];
  const int b = blockIdx.x, tid = threadIdx.x;
  const int lane = tid & 63, wv = tid >> 6;
  const unsigned e0 = bbase[b], e1 = bbase[b + 1];
  const int nb0 = b << 10;
  hist[tid] = 0;
  __syncthreads();
  for (unsigned j = e0 + tid; j < e1; j += 1024)
    atomicAdd(&hist[pairs[j] & 1023u], 1u);
  __syncthreads();
  unsigned v = hist[tid];
  unsigned s = v;
  #pragma unroll
  for (int off = 1; off < 64; off <<= 1){
    unsigned u = __shfl_up(s, off, 64);
    if (lane >= off) s += u;
  }
  if (lane == 63) wsum[wv] = s;
  __syncthreads();
  unsigned woff = 0;
  for (int w = 0; w < wv; ++w) woff += wsum[w];
  unsigned gpos = e0 + woff + s - v;          // global start of this node's segment
  if (nb0 + tid < NNODE) rowptr[nb0 + tid] = gpos;
  __syncthreads();
  hist[tid] = gpos;                            // reuse as cursor
  __syncthreads();
  for (unsigned j = e0 + tid; j < e1; j += 1024){
    unsigned e = pairs[j];
    unsigned p = atomicAdd(&hist[e & 1023u], 1u);
    col[p] = e >> 10;
  }
}

// ---------------- conversions ----------------
__global__ void k_xcvt(const float* __restrict__ x, unsigned* __restrict__ A1u){
  int i = blockIdx.x * 256 + threadIdx.x;   // over N*32 float4s
  if (i >= NNODE * 32) return;
  float4 v = ((const float4*)x)[i];
  int e = i * 4;
  int row = e >> 7, c = e & 127;
  unsigned* d = A1u + (size_t)row * 128 + 64 + (c >> 1);
  d[0] = pk2(v.x, v.y);
  d[1] = pk2(v.z, v.w);
}

__global__ void k_wcvt1(const float* __restrict__ W1l, const float* __restrict__ W1r,
                        unsigned short* __restrict__ Bwt1){
  int i = blockIdx.x * 256 + threadIdx.x;
  if (i >= 256 * 256) return;
  int n = i >> 8, k = i & 255;
  float v = (k < 128) ? W1l[n * 128 + k] : W1r[n * 128 + (k - 128)];
  Bwt1[i] = f2bf(v);
}

__global__ void k_wcvt2(const float* __restrict__ W2l, const float* __restrict__ W2r,
                        unsigned short* __restrict__ Bwt2){
  int i = blockIdx.x * 256 + threadIdx.x;
  if (i >= 128 * 256) return;
  int n = i >> 8, k = i & 255;
  float v = (n < 64) ? W2l[n * 256 + k] : W2r[(n - 64) * 256 + k];
  Bwt2[i] = f2bf(v);
}

// ---------------- layer-1 aggregation (unroll 4 for MLP) ----------------
__global__ __launch_bounds__(256) void k_agg1(const unsigned* __restrict__ rowptr,
                                              const unsigned* __restrict__ col,
                                              unsigned* __restrict__ A1u){
  int gw = (blockIdx.x * 256 + threadIdx.x) >> 6;
  int lane = threadIdx.x & 63;
  if (gw >= NNODE) return;
  unsigned s0 = rowptr[gw], s1 = rowptr[gw + 1];
  float ax = 0.f, ay = 0.f;
  unsigned j = s0;
  for (; j + 3 < s1; j += 4){
    unsigned c0 = col[j], c1 = col[j+1], c2 = col[j+2], c3 = col[j+3];
    unsigned v0 = A1u[(size_t)c0 * 128 + 64 + lane];
    unsigned v1 = A1u[(size_t)c1 * 128 + 64 + lane];
    unsigned v2 = A1u[(size_t)c2 * 128 + 64 + lane];
    unsigned v3 = A1u[(size_t)c3 * 128 + 64 + lane];
    ax += bflo(v0) + bflo(v1) + bflo(v2) + bflo(v3);
    ay += bfhi(v0) + bfhi(v1) + bfhi(v2) + bfhi(v3);
  }
  for (; j < s1; ++j){
    unsigned v = A1u[(size_t)col[j] * 128 + 64 + lane];
    ax += bflo(v); ay += bfhi(v);
  }
  float inv = 1.f / fmaxf((float)(s1 - s0), 1.f);
  A1u[(size_t)gw * 128 + lane] = pk2(ax * inv, ay * inv);
}

// ---------------- MFMA GEMM ----------------
template<int BN, bool RELU, bool BIAS>
__global__ __launch_bounds__(256) void k_gemm(const unsigned short* __restrict__ A,
                                              const unsigned short* __restrict__ B,
                                              const float* __restrict__ bias,
                                              unsigned short* __restrict__ C,
                                              int nrows){
  constexpr int NF = BN / 64;
  __shared__ unsigned short a_t[64 * 64];
  __shared__ unsigned short b_t[BN * 64];
  const int tid = threadIdx.x, wave = tid >> 6, lane = tid & 63;
  const int row0 = blockIdx.x * 64;
  char* ab = (char*)a_t;
  char* bb = (char*)b_t;

  f32x4 acc[4][NF];
  #pragma unroll
  for (int m = 0; m < 4; ++m)
    #pragma unroll
    for (int n = 0; n < NF; ++n)
      acc[m][n] = (f32x4){0.f, 0.f, 0.f, 0.f};

  for (int kt = 0; kt < 4; ++kt){
    {
      int r = tid >> 2;
      int gr = row0 + r; if (gr > nrows - 1) gr = nrows - 1;
      const uint4* s4 = (const uint4*)(A + (size_t)gr * 256 + kt * 64);
      int c0 = (tid & 3) * 2;
      uint4 v0 = s4[c0], v1 = s4[c0 + 1];
      *(uint4*)(ab + r * 128 + ((c0 * 16) ^ ((r & 7) << 4))) = v0;
      *(uint4*)(ab + r * 128 + (((c0 + 1) * 16) ^ ((r & 7) << 4))) = v1;
    }
    {
      constexpr int CPT = BN / 32;
      #pragma unroll
      for (int c = 0; c < CPT; ++c){
        int gc = tid * CPT + c;
        int n = gc >> 3, ck = gc & 7;
        uint4 v = ((const uint4*)(B + (size_t)n * 256 + kt * 64))[ck];
        *(uint4*)(bb + n * 128 + ((ck * 16) ^ ((n & 7) << 4))) = v;
      }
    }
    __syncthreads();
    #pragma unroll
    for (int kk = 0; kk < 2; ++kk){
      int k2 = (kk * 32 + ((lane >> 4) * 8)) * 2;
      bf16x8 af[4];
      #pragma unroll
      for (int m = 0; m < 4; ++m){
        int rr = m * 16 + (lane & 15);
        af[m] = *(const bf16x8*)(ab + rr * 128 + (k2 ^ ((rr & 7) << 4)));
      }
      #pragma unroll
      for (int n = 0; n < NF; ++n){
        int cc = wave * (16 * NF) + n * 16 + (lane & 15);
        bf16x8 bfv = *(const bf16x8*)(bb + cc * 128 + (k2 ^ ((cc & 7) << 4)));
        #pragma unroll
        for (int m = 0; m < 4; ++m)
          acc[m][n] = __builtin_amdgcn_mfma_f32_16x16x32_bf16(af[m], bfv, acc[m][n], 0, 0, 0);
      }
    }
    __syncthreads();
  }
  #pragma unroll
  for (int m = 0; m < 4; ++m){
    int rbase = row0 + m * 16 + ((lane >> 4) << 2);
    #pragma unroll
    for (int r = 0; r < 4; ++r){
      if (rbase + r < nrows){
        #pragma unroll
        for (int n = 0; n < NF; ++n){
          int cc = wave * (16 * NF) + n * 16 + (lane & 15);
          float v = acc[m][n][r];
          if (BIAS) v += bias[cc];
          if (RELU) v = fmaxf(v, 0.f);
          C[(size_t)(rbase + r) * BN + cc] = f2bf(v);
        }
      }
    }
  }
}

// ---------------- layer-2 aggregation + residual + bias (unroll 4) ----------------
__global__ __launch_bounds__(256) void k_agg2(const unsigned* __restrict__ rowptr,
                                              const unsigned* __restrict__ col,
                                              const unsigned short* __restrict__ zr,
                                              const float* __restrict__ b2,
                                              float* __restrict__ out){
  int t = blockIdx.x * 256 + threadIdx.x;
  int node = t >> 4, gl = t & 15;
  if (node >= NNODE) return;
  unsigned s0 = rowptr[node], s1 = rowptr[node + 1];
  float a0 = 0.f, a1 = 0.f, a2 = 0.f, a3 = 0.f;
  unsigned j = s0;
  for (; j + 3 < s1; j += 4){
    unsigned c0 = col[j], c1 = col[j+1], c2 = col[j+2], c3 = col[j+3];
    uint2 v0 = *(const uint2*)(zr + (size_t)c0 * 128 + gl * 4);
    uint2 v1 = *(const uint2*)(zr + (size_t)c1 * 128 + gl * 4);
    uint2 v2 = *(const uint2*)(zr + (size_t)c2 * 128 + gl * 4);
    uint2 v3 = *(const uint2*)(zr + (size_t)c3 * 128 + gl * 4);
    a0 += bflo(v0.x) + bflo(v1.x) + bflo(v2.x) + bflo(v3.x);
    a1 += bfhi(v0.x) + bfhi(v1.x) + bfhi(v2.x) + bfhi(v3.x);
    a2 += bflo(v0.y) + bflo(v1.y) + bflo(v2.y) + bflo(v3.y);
    a3 += bfhi(v0.y) + bfhi(v1.y) + bfhi(v2.y) + bfhi(v3.y);
  }
  for (; j < s1; ++j){
    uint2 v = *(const uint2*)(zr + (size_t)col[j] * 128 + gl * 4);
    a0 += bflo(v.x); a1 += bfhi(v.x); a2 += bflo(v.y); a3 += bfhi(v.y);
  }
  float inv = 1.f / fmaxf((float)(s1 - s0), 1.f);
  uint2 rv = *(const uint2*)(zr + (size_t)node * 128 + 64 + gl * 4);
  float4 res;
  res.x = a0 * inv + bflo(rv.x) + b2[gl * 4 + 0];
  res.y = a1 * inv + bfhi(rv.x) + b2[gl * 4 + 1];
  res.z = a2 * inv + bflo(rv.y) + b2[gl * 4 + 2];
  res.w = a3 * inv + bfhi(rv.y) + b2[gl * 4 + 3];
  ((float4*)out)[(size_t)node * 16 + gl] = res;
}

extern "C" void kernel_launch(void* const* d_in, const int* in_sizes, int n_in,
                              void* d_out, int out_size, void* d_ws, size_t ws_size,
                              hipStream_t stream) {
  const float* x   = (const float*)d_in[0];
  const int*   ei  = (const int*)d_in[1];
  const float* W1l = (const float*)d_in[2];
  const float* b1  = (const float*)d_in[3];
  const float* W1r = (const float*)d_in[4];
  const float* W2l = (const float*)d_in[5];
  const float* b2  = (const float*)d_in[6];
  const float* W2r = (const float*)d_in[7];
  float* out = (float*)d_out;

  char* ws = (char*)d_ws;
  size_t off = 0;
  auto alloc = [&](size_t bytes) -> void* {
    void* p = ws + off;
    off = (off + bytes + 255) & ~(size_t)255;
    return p;
  };
  unsigned* rowptr = (unsigned*)alloc((size_t)(NNODE + 1) * 4);
  unsigned* col    = (unsigned*)alloc((size_t)NEDGE * 4);
  unsigned* pairs  = (unsigned*)alloc((size_t)NEDGE * 4);
  unsigned* gh     = (unsigned*)alloc((size_t)NBBLK * NB2 * 4);
  unsigned* gbase  = (unsigned*)alloc((size_t)NBBLK * NB2 * 4);
  unsigned* btot   = (unsigned*)alloc((size_t)NB2 * 4);
  unsigned* bbase  = (unsigned*)alloc((size_t)(NB2 + 1) * 4);
  unsigned short* A1   = (unsigned short*)alloc((size_t)NNODE * 256 * 2);
  unsigned short* h    = (unsigned short*)alloc((size_t)NNODE * 256 * 2);
  unsigned short* zr   = (unsigned short*)alloc((size_t)NNODE * 128 * 2);
  unsigned short* Bwt1 = (unsigned short*)alloc(256 * 256 * 2);
  unsigned short* Bwt2 = (unsigned short*)alloc(128 * 256 * 2);

  const int* srcv = ei;
  const int* dstv = ei + NEDGE;

  k_hist<<<NBBLK, 256, 0, stream>>>(dstv, gh);
  k_scan512<<<NB2, 512, 0, stream>>>(gh, gbase, btot);
  k_scanb<<<1, 128, 0, stream>>>(btot, bbase, rowptr);
  k_binscat<<<NBBLK, 256, 0, stream>>>(srcv, dstv, gbase, bbase, pairs);
  k_buildcsr<<<NB2, 1024, 0, stream>>>(bbase, pairs, rowptr, col);

  k_xcvt<<<(NNODE * 32 + 255) / 256, 256, 0, stream>>>(x, (unsigned*)A1);
  k_wcvt1<<<256, 256, 0, stream>>>(W1l, W1r, Bwt1);
  k_wcvt2<<<128, 256, 0, stream>>>(W2l, W2r, Bwt2);

  k_agg1<<<(NNODE + 3) / 4, 256, 0, stream>>>(rowptr, col, (unsigned*)A1);

  int gblocks = (NNODE + 63) / 64;
  k_gemm<256, true,  true ><<<gblocks, 256, 0, stream>>>(A1, Bwt1, b1, h, NNODE);
  k_gemm<128, false, false><<<gblocks, 256, 0, stream>>>(h,  Bwt2, nullptr, zr, NNODE);

  k_agg2<<<(NNODE * 16 + 255) / 256, 256, 0, stream>>>(rowptr, col, zr, b2, out);
}

// Round 6
// 324.779 us; speedup vs baseline: 1.6025x; 1.0184x over previous
//
#include <hip/hip_runtime.h>
#include <hip/hip_bf16.h>

#define NNODE 100000
#define NEDGE 1600000
#define NBBLK 512
#define CHUNK (NEDGE / NBBLK)              // 3125 edges per binning block
#define NB2 ((NNODE + 1023) >> 10)         // 98 buckets of 1024 dst-nodes

typedef __attribute__((ext_vector_type(8))) short bf16x8;
typedef __attribute__((ext_vector_type(4))) float f32x4;
typedef __attribute__((ext_vector_type(2))) float f32x2;

__device__ __forceinline__ unsigned short f2bf(float f){
  unsigned u = __float_as_uint(f);
  u += 0x7fffu + ((u >> 16) & 1u);
  return (unsigned short)(u >> 16);
}
__device__ __forceinline__ unsigned pk2(float a, float b){
  return (unsigned)f2bf(a) | ((unsigned)f2bf(b) << 16);
}
__device__ __forceinline__ float bflo(unsigned v){ return __uint_as_float(v << 16); }
__device__ __forceinline__ float bfhi(unsigned v){ return __uint_as_float(v & 0xffff0000u); }

// ---------------- CSR build: deterministic 2-pass binning ----------------
__global__ __launch_bounds__(256) void k_hist(const int* __restrict__ dst,
                                              unsigned* __restrict__ gh){
  __shared__ unsigned h[NB2];
  for (int t = threadIdx.x; t < NB2; t += 256) h[t] = 0;
  __syncthreads();
  int base = blockIdx.x * CHUNK;
  for (int j = threadIdx.x; j < CHUNK; j += 256)
    atomicAdd(&h[dst[base + j] >> 10], 1u);
  __syncthreads();
  for (int t = threadIdx.x; t < NB2; t += 256) gh[blockIdx.x * NB2 + t] = h[t];
}

__global__ __launch_bounds__(512) void k_scan512(const unsigned* __restrict__ gh,
                                                 unsigned* __restrict__ gbase,
                                                 unsigned* __restrict__ btot){
  int b = blockIdx.x, t = threadIdx.x;
  int lane = t & 63, wv = t >> 6;
  unsigned v = gh[t * NB2 + b];
  unsigned s = v;
  #pragma unroll
  for (int off = 1; off < 64; off <<= 1){
    unsigned u = __shfl_up(s, off, 64);
    if (lane >= off) s += u;
  }
  __shared__ unsigned wsum[8];
  if (lane == 63) wsum[wv] = s;
  __syncthreads();
  unsigned woff = 0;
  for (int w = 0; w < wv; ++w) woff += wsum[w];
  gbase[t * NB2 + b] = woff + s - v;
  if (t == 511) btot[b] = woff + s;
}

__global__ __launch_bounds__(128) void k_scanb(const unsigned* __restrict__ btot,
                                               unsigned* __restrict__ bbase,
                                               unsigned* __restrict__ rowptr){
  __shared__ unsigned buf[128];
  int tid = threadIdx.x;
  unsigned v = (tid < NB2) ? btot[tid] : 0u;
  buf[tid] = v;
  __syncthreads();
  #pragma unroll
  for (int off = 1; off < 128; off <<= 1){
    unsigned t = (tid >= off) ? buf[tid - off] : 0u;
    __syncthreads();
    buf[tid] += t;
    __syncthreads();
  }
  if (tid < NB2) bbase[tid] = buf[tid] - v;
  if (tid == 0){ bbase[NB2] = NEDGE; rowptr[NNODE] = NEDGE; }
}

__global__ __launch_bounds__(256) void k_binscat(const int* __restrict__ src,
                                                 const int* __restrict__ dst,
                                                 const unsigned* __restrict__ gbase,
                                                 const unsigned* __restrict__ bbase,
                                                 unsigned* __restrict__ pairs){
  __shared__ unsigned cur[NB2];
  for (int t = threadIdx.x; t < NB2; t += 256)
    cur[t] = bbase[t] + gbase[blockIdx.x * NB2 + t];
  __syncthreads();
  int base = blockIdx.x * CHUNK;
  for (int j = threadIdx.x; j < CHUNK; j += 256){
    int s = src[base + j], d = dst[base + j];
    unsigned p = atomicAdd(&cur[d >> 10], 1u);
    pairs[p] = ((unsigned)s << 10) | (unsigned)(d & 1023);
  }
}

__global__ __launch_bounds__(1024) void k_buildcsr(const unsigned* __restrict__ bbase,
                                                   const unsigned* __restrict__ pairs,
                                                   unsigned* __restrict__ rowptr,
                                                   unsigned* __restrict__ col){
  __shared__ unsigned hist[1024];
  __shared__ unsigned wsum[16];
  const int b = blockIdx.x, tid = threadIdx.x;
  const int lane = tid & 63, wv = tid >> 6;
  const unsigned e0 = bbase[b], e1 = bbase[b + 1];
  const int nb0 = b << 10;
  hist[tid] = 0;
  __syncthreads();
  for (unsigned j = e0 + tid; j < e1; j += 1024)
    atomicAdd(&hist[pairs[j] & 1023u], 1u);
  __syncthreads();
  unsigned v = hist[tid];
  unsigned s = v;
  #pragma unroll
  for (int off = 1; off < 64; off <<= 1){
    unsigned u = __shfl_up(s, off, 64);
    if (lane >= off) s += u;
  }
  if (lane == 63) wsum[wv] = s;
  __syncthreads();
  unsigned woff = 0;
  for (int w = 0; w < wv; ++w) woff += wsum[w];
  unsigned gpos = e0 + woff + s - v;
  if (nb0 + tid < NNODE) rowptr[nb0 + tid] = gpos;
  __syncthreads();
  hist[tid] = gpos;
  __syncthreads();
  for (unsigned j = e0 + tid; j < e1; j += 1024){
    unsigned e = pairs[j];
    unsigned p = atomicAdd(&hist[e & 1023u], 1u);
    col[p] = e >> 10;
  }
}

// ---------------- conversions ----------------
// x fp32 -> bf16 (A1 cols 128..255) AND fp8 e4m3 side copy (x8, [N,128])
__global__ void k_xcvt(const float* __restrict__ x, unsigned* __restrict__ A1u,
                       unsigned* __restrict__ x8u){
  int i = blockIdx.x * 256 + threadIdx.x;   // over N*32 float4s
  if (i >= NNODE * 32) return;
  float4 v = ((const float4*)x)[i];
  int e = i * 4;
  int row = e >> 7, c = e & 127;
  unsigned* d = A1u + (size_t)row * 128 + 64 + (c >> 1);
  d[0] = pk2(v.x, v.y);
  d[1] = pk2(v.z, v.w);
  unsigned p = (unsigned)__builtin_amdgcn_cvt_pk_fp8_f32(v.x, v.y, 0, false);
  p = (unsigned)__builtin_amdgcn_cvt_pk_fp8_f32(v.z, v.w, (int)p, true);
  x8u[(size_t)row * 32 + (c >> 2)] = p;
}

__global__ void k_wcvt1(const float* __restrict__ W1l, const float* __restrict__ W1r,
                        unsigned short* __restrict__ Bwt1){
  int i = blockIdx.x * 256 + threadIdx.x;
  if (i >= 256 * 256) return;
  int n = i >> 8, k = i & 255;
  float v = (k < 128) ? W1l[n * 128 + k] : W1r[n * 128 + (k - 128)];
  Bwt1[i] = f2bf(v);
}

__global__ void k_wcvt2(const float* __restrict__ W2l, const float* __restrict__ W2r,
                        unsigned short* __restrict__ Bwt2){
  int i = blockIdx.x * 256 + threadIdx.x;
  if (i >= 128 * 256) return;
  int n = i >> 8, k = i & 255;
  float v = (n < 64) ? W2l[n * 256 + k] : W2r[(n - 64) * 256 + k];
  Bwt2[i] = f2bf(v);
}

// z (zr cols 0..63, bf16) -> fp8 (z8, [N,64])
__global__ void k_zcvt(const unsigned* __restrict__ zru, unsigned* __restrict__ z8u){
  int i = blockIdx.x * 256 + threadIdx.x;   // N*16
  if (i >= NNODE * 16) return;
  int node = i >> 4, g = i & 15;
  uint2 v = ((const uint2*)(zru + (size_t)node * 64))[g];
  unsigned p = (unsigned)__builtin_amdgcn_cvt_pk_fp8_f32(bflo(v.x), bfhi(v.x), 0, false);
  p = (unsigned)__builtin_amdgcn_cvt_pk_fp8_f32(bflo(v.y), bfhi(v.y), (int)p, true);
  z8u[(size_t)node * 16 + g] = p;
}

// ---------------- layer-1 aggregation: fp8 gather, 4 edges per wave-load ----------------
// one wave per node; 16-lane group per edge; lane (l&15) holds dims 8u..8u+7 via uint2
__global__ __launch_bounds__(256) void k_agg1(const unsigned* __restrict__ rowptr,
                                              const unsigned* __restrict__ col,
                                              const unsigned* __restrict__ x8u,
                                              unsigned* __restrict__ A1u){
  int gw = (blockIdx.x * 256 + threadIdx.x) >> 6;
  int lane = threadIdx.x & 63;
  if (gw >= NNODE) return;
  unsigned s0 = rowptr[gw], s1 = rowptr[gw + 1];
  const int sel = lane >> 4, u = lane & 15;
  const uint2* x82 = (const uint2*)x8u;
  float a0=0.f,a1=0.f,a2=0.f,a3=0.f,a4=0.f,a5=0.f,a6=0.f,a7=0.f;
  unsigned j = s0;
  for (; j + 7 < s1; j += 8){
    unsigned ca = col[j + sel], cb = col[j + 4 + sel];
    uint2 va = x82[(size_t)ca * 16 + u];
    uint2 vb = x82[(size_t)cb * 16 + u];
    f32x2 p;
    p = __builtin_amdgcn_cvt_pk_f32_fp8((int)va.x, false); a0+=p.x; a1+=p.y;
    p = __builtin_amdgcn_cvt_pk_f32_fp8((int)va.x, true ); a2+=p.x; a3+=p.y;
    p = __builtin_amdgcn_cvt_pk_f32_fp8((int)va.y, false); a4+=p.x; a5+=p.y;
    p = __builtin_amdgcn_cvt_pk_f32_fp8((int)va.y, true ); a6+=p.x; a7+=p.y;
    p = __builtin_amdgcn_cvt_pk_f32_fp8((int)vb.x, false); a0+=p.x; a1+=p.y;
    p = __builtin_amdgcn_cvt_pk_f32_fp8((int)vb.x, true ); a2+=p.x; a3+=p.y;
    p = __builtin_amdgcn_cvt_pk_f32_fp8((int)vb.y, false); a4+=p.x; a5+=p.y;
    p = __builtin_amdgcn_cvt_pk_f32_fp8((int)vb.y, true ); a6+=p.x; a7+=p.y;
  }
  for (; j + 3 < s1; j += 4){
    unsigned ca = col[j + sel];
    uint2 va = x82[(size_t)ca * 16 + u];
    f32x2 p;
    p = __builtin_amdgcn_cvt_pk_f32_fp8((int)va.x, false); a0+=p.x; a1+=p.y;
    p = __builtin_amdgcn_cvt_pk_f32_fp8((int)va.x, true ); a2+=p.x; a3+=p.y;
    p = __builtin_amdgcn_cvt_pk_f32_fp8((int)va.y, false); a4+=p.x; a5+=p.y;
    p = __builtin_amdgcn_cvt_pk_f32_fp8((int)va.y, true ); a6+=p.x; a7+=p.y;
  }
  int rem = (int)(s1 - j);
  if (sel < rem){
    unsigned ca = col[j + sel];
    uint2 va = x82[(size_t)ca * 16 + u];
    f32x2 p;
    p = __builtin_amdgcn_cvt_pk_f32_fp8((int)va.x, false); a0+=p.x; a1+=p.y;
    p = __builtin_amdgcn_cvt_pk_f32_fp8((int)va.x, true ); a2+=p.x; a3+=p.y;
    p = __builtin_amdgcn_cvt_pk_f32_fp8((int)va.y, false); a4+=p.x; a5+=p.y;
    p = __builtin_amdgcn_cvt_pk_f32_fp8((int)va.y, true ); a6+=p.x; a7+=p.y;
  }
  // reduce the 4 edge-groups
  a0 += __shfl_xor(a0, 16, 64); a1 += __shfl_xor(a1, 16, 64);
  a2 += __shfl_xor(a2, 16, 64); a3 += __shfl_xor(a3, 16, 64);
  a4 += __shfl_xor(a4, 16, 64); a5 += __shfl_xor(a5, 16, 64);
  a6 += __shfl_xor(a6, 16, 64); a7 += __shfl_xor(a7, 16, 64);
  a0 += __shfl_xor(a0, 32, 64); a1 += __shfl_xor(a1, 32, 64);
  a2 += __shfl_xor(a2, 32, 64); a3 += __shfl_xor(a3, 32, 64);
  a4 += __shfl_xor(a4, 32, 64); a5 += __shfl_xor(a5, 32, 64);
  a6 += __shfl_xor(a6, 32, 64); a7 += __shfl_xor(a7, 32, 64);
  if (lane < 16){
    float inv = 1.f / fmaxf((float)(s1 - s0), 1.f);
    uint4 w;
    w.x = pk2(a0 * inv, a1 * inv);
    w.y = pk2(a2 * inv, a3 * inv);
    w.z = pk2(a4 * inv, a5 * inv);
    w.w = pk2(a6 * inv, a7 * inv);
    *(uint4*)(A1u + (size_t)gw * 128 + 4 * lane) = w;
  }
}

// ---------------- MFMA GEMM ----------------
template<int BN, bool RELU, bool BIAS>
__global__ __launch_bounds__(256) void k_gemm(const unsigned short* __restrict__ A,
                                              const unsigned short* __restrict__ B,
                                              const float* __restrict__ bias,
                                              unsigned short* __restrict__ C,
                                              int nrows){
  constexpr int NF = BN / 64;
  __shared__ unsigned short a_t[64 * 64];
  __shared__ unsigned short b_t[BN * 64];
  const int tid = threadIdx.x, wave = tid >> 6, lane = tid & 63;
  const int row0 = blockIdx.x * 64;
  char* ab = (char*)a_t;
  char* bb = (char*)b_t;

  f32x4 acc[4][NF];
  #pragma unroll
  for (int m = 0; m < 4; ++m)
    #pragma unroll
    for (int n = 0; n < NF; ++n)
      acc[m][n] = (f32x4){0.f, 0.f, 0.f, 0.f};

  for (int kt = 0; kt < 4; ++kt){
    {
      int r = tid >> 2;
      int gr = row0 + r; if (gr > nrows - 1) gr = nrows - 1;
      const uint4* s4 = (const uint4*)(A + (size_t)gr * 256 + kt * 64);
      int c0 = (tid & 3) * 2;
      uint4 v0 = s4[c0], v1 = s4[c0 + 1];
      *(uint4*)(ab + r * 128 + ((c0 * 16) ^ ((r & 7) << 4))) = v0;
      *(uint4*)(ab + r * 128 + (((c0 + 1) * 16) ^ ((r & 7) << 4))) = v1;
    }
    {
      constexpr int CPT = BN / 32;
      #pragma unroll
      for (int c = 0; c < CPT; ++c){
        int gc = tid * CPT + c;
        int n = gc >> 3, ck = gc & 7;
        uint4 v = ((const uint4*)(B + (size_t)n * 256 + kt * 64))[ck];
        *(uint4*)(bb + n * 128 + ((ck * 16) ^ ((n & 7) << 4))) = v;
      }
    }
    __syncthreads();
    #pragma unroll
    for (int kk = 0; kk < 2; ++kk){
      int k2 = (kk * 32 + ((lane >> 4) * 8)) * 2;
      bf16x8 af[4];
      #pragma unroll
      for (int m = 0; m < 4; ++m){
        int rr = m * 16 + (lane & 15);
        af[m] = *(const bf16x8*)(ab + rr * 128 + (k2 ^ ((rr & 7) << 4)));
      }
      #pragma unroll
      for (int n = 0; n < NF; ++n){
        int cc = wave * (16 * NF) + n * 16 + (lane & 15);
        bf16x8 bfv = *(const bf16x8*)(bb + cc * 128 + (k2 ^ ((cc & 7) << 4)));
        #pragma unroll
        for (int m = 0; m < 4; ++m)
          acc[m][n] = __builtin_amdgcn_mfma_f32_16x16x32_bf16(af[m], bfv, acc[m][n], 0, 0, 0);
      }
    }
    __syncthreads();
  }
  #pragma unroll
  for (int m = 0; m < 4; ++m){
    int rbase = row0 + m * 16 + ((lane >> 4) << 2);
    #pragma unroll
    for (int r = 0; r < 4; ++r){
      if (rbase + r < nrows){
        #pragma unroll
        for (int n = 0; n < NF; ++n){
          int cc = wave * (16 * NF) + n * 16 + (lane & 15);
          float v = acc[m][n][r];
          if (BIAS) v += bias[cc];
          if (RELU) v = fmaxf(v, 0.f);
          C[(size_t)(rbase + r) * BN + cc] = f2bf(v);
        }
      }
    }
  }
}

// ---------------- layer-2 aggregation: fp8 gather + residual + bias ----------------
// one wave per node; 16-lane group per edge; lane (l&15) holds dims 4u..4u+3 via uint
__global__ __launch_bounds__(256) void k_agg2(const unsigned* __restrict__ rowptr,
                                              const unsigned* __restrict__ col,
                                              const unsigned* __restrict__ z8u,
                                              const unsigned* __restrict__ zru,
                                              const float* __restrict__ b2,
                                              float* __restrict__ out){
  int gw = (blockIdx.x * 256 + threadIdx.x) >> 6;
  int lane = threadIdx.x & 63;
  if (gw >= NNODE) return;
  unsigned s0 = rowptr[gw], s1 = rowptr[gw + 1];
  const int sel = lane >> 4, u = lane & 15;
  float a0=0.f,a1=0.f,a2=0.f,a3=0.f;
  unsigned j = s0;
  for (; j + 7 < s1; j += 8){
    unsigned ca = col[j + sel], cb = col[j + 4 + sel];
    unsigned va = z8u[(size_t)ca * 16 + u];
    unsigned vb = z8u[(size_t)cb * 16 + u];
    f32x2 p;
    p = __builtin_amdgcn_cvt_pk_f32_fp8((int)va, false); a0+=p.x; a1+=p.y;
    p = __builtin_amdgcn_cvt_pk_f32_fp8((int)va, true ); a2+=p.x; a3+=p.y;
    p = __builtin_amdgcn_cvt_pk_f32_fp8((int)vb, false); a0+=p.x; a1+=p.y;
    p = __builtin_amdgcn_cvt_pk_f32_fp8((int)vb, true ); a2+=p.x; a3+=p.y;
  }
  for (; j + 3 < s1; j += 4){
    unsigned ca = col[j + sel];
    unsigned va = z8u[(size_t)ca * 16 + u];
    f32x2 p;
    p = __builtin_amdgcn_cvt_pk_f32_fp8((int)va, false); a0+=p.x; a1+=p.y;
    p = __builtin_amdgcn_cvt_pk_f32_fp8((int)va, true ); a2+=p.x; a3+=p.y;
  }
  int rem = (int)(s1 - j);
  if (sel < rem){
    unsigned ca = col[j + sel];
    unsigned va = z8u[(size_t)ca * 16 + u];
    f32x2 p;
    p = __builtin_amdgcn_cvt_pk_f32_fp8((int)va, false); a0+=p.x; a1+=p.y;
    p = __builtin_amdgcn_cvt_pk_f32_fp8((int)va, true ); a2+=p.x; a3+=p.y;
  }
  a0 += __shfl_xor(a0, 16, 64); a1 += __shfl_xor(a1, 16, 64);
  a2 += __shfl_xor(a2, 16, 64); a3 += __shfl_xor(a3, 16, 64);
  a0 += __shfl_xor(a0, 32, 64); a1 += __shfl_xor(a1, 32, 64);
  a2 += __shfl_xor(a2, 32, 64); a3 += __shfl_xor(a3, 32, 64);
  if (lane < 16){
    float inv = 1.f / fmaxf((float)(s1 - s0), 1.f);
    uint2 rv = ((const uint2*)(zru + (size_t)gw * 64 + 32))[lane];
    float4 bv = ((const float4*)b2)[lane];
    float4 res;
    res.x = a0 * inv + bflo(rv.x) + bv.x;
    res.y = a1 * inv + bfhi(rv.x) + bv.y;
    res.z = a2 * inv + bflo(rv.y) + bv.z;
    res.w = a3 * inv + bfhi(rv.y) + bv.w;
    ((float4*)out)[(size_t)gw * 16 + lane] = res;
  }
}

extern "C" void kernel_launch(void* const* d_in, const int* in_sizes, int n_in,
                              void* d_out, int out_size, void* d_ws, size_t ws_size,
                              hipStream_t stream) {
  const float* x   = (const float*)d_in[0];
  const int*   ei  = (const int*)d_in[1];
  const float* W1l = (const float*)d_in[2];
  const float* b1  = (const float*)d_in[3];
  const float* W1r = (const float*)d_in[4];
  const float* W2l = (const float*)d_in[5];
  const float* b2  = (const float*)d_in[6];
  const float* W2r = (const float*)d_in[7];
  float* out = (float*)d_out;

  char* ws = (char*)d_ws;
  size_t off = 0;
  auto alloc = [&](size_t bytes) -> void* {
    void* p = ws + off;
    off = (off + bytes + 255) & ~(size_t)255;
    return p;
  };
  unsigned* rowptr = (unsigned*)alloc((size_t)(NNODE + 1) * 4);
  unsigned* col    = (unsigned*)alloc((size_t)NEDGE * 4);
  unsigned* pairs  = (unsigned*)alloc((size_t)NEDGE * 4);
  unsigned* gh     = (unsigned*)alloc((size_t)NBBLK * NB2 * 4);
  unsigned* gbase  = (unsigned*)alloc((size_t)NBBLK * NB2 * 4);
  unsigned* btot   = (unsigned*)alloc((size_t)NB2 * 4);
  unsigned* bbase  = (unsigned*)alloc((size_t)(NB2 + 1) * 4);
  unsigned short* A1   = (unsigned short*)alloc((size_t)NNODE * 256 * 2);
  unsigned short* h    = (unsigned short*)alloc((size_t)NNODE * 256 * 2);
  unsigned short* zr   = (unsigned short*)alloc((size_t)NNODE * 128 * 2);
  unsigned* x8u        = (unsigned*)alloc((size_t)NNODE * 32 * 4);
  unsigned* z8u        = (unsigned*)alloc((size_t)NNODE * 16 * 4);
  unsigned short* Bwt1 = (unsigned short*)alloc(256 * 256 * 2);
  unsigned short* Bwt2 = (unsigned short*)alloc(128 * 256 * 2);

  const int* srcv = ei;
  const int* dstv = ei + NEDGE;

  k_hist<<<NBBLK, 256, 0, stream>>>(dstv, gh);
  k_scan512<<<NB2, 512, 0, stream>>>(gh, gbase, btot);
  k_scanb<<<1, 128, 0, stream>>>(btot, bbase, rowptr);
  k_binscat<<<NBBLK, 256, 0, stream>>>(srcv, dstv, gbase, bbase, pairs);
  k_buildcsr<<<NB2, 1024, 0, stream>>>(bbase, pairs, rowptr, col);

  k_xcvt<<<(NNODE * 32 + 255) / 256, 256, 0, stream>>>(x, (unsigned*)A1, x8u);
  k_wcvt1<<<256, 256, 0, stream>>>(W1l, W1r, Bwt1);
  k_wcvt2<<<128, 256, 0, stream>>>(W2l, W2r, Bwt2);

  k_agg1<<<(NNODE + 3) / 4, 256, 0, stream>>>(rowptr, col, x8u, (unsigned*)A1);

  int gblocks = (NNODE + 63) / 64;
  k_gemm<256, true,  true ><<<gblocks, 256, 0, stream>>>(A1, Bwt1, b1, h, NNODE);
  k_gemm<128, false, false><<<gblocks, 256, 0, stream>>>(h,  Bwt2, nullptr, zr, NNODE);

  k_zcvt<<<(NNODE * 16 + 255) / 256, 256, 0, stream>>>((const unsigned*)zr, z8u);
  k_agg2<<<(NNODE + 3) / 4, 256, 0, stream>>>(rowptr, col, z8u, (const unsigned*)zr, b2, out);
}

// Round 7
// 318.701 us; speedup vs baseline: 1.6330x; 1.0191x over previous
//
#include <hip/hip_runtime.h>
#include <hip/hip_bf16.h>

#define NNODE 100000
#define NEDGE 1600000
#define NBBLK 512
#define CHUNK (NEDGE / NBBLK)              // 3125 edges per binning block
#define NB2 ((NNODE + 1023) >> 10)         // 98 buckets of 1024 dst-nodes

typedef __attribute__((ext_vector_type(8))) short bf16x8;
typedef __attribute__((ext_vector_type(4))) float f32x4;
typedef __attribute__((ext_vector_type(2))) float f32x2;

__device__ __forceinline__ unsigned short f2bf(float f){
  unsigned u = __float_as_uint(f);
  u += 0x7fffu + ((u >> 16) & 1u);
  return (unsigned short)(u >> 16);
}
__device__ __forceinline__ unsigned pk2(float a, float b){
  return (unsigned)f2bf(a) | ((unsigned)f2bf(b) << 16);
}
__device__ __forceinline__ float bflo(unsigned v){ return __uint_as_float(v << 16); }
__device__ __forceinline__ float bfhi(unsigned v){ return __uint_as_float(v & 0xffff0000u); }

// ---------------- fused: x conversion (bf16 + fp8) AND edge histogram ----------------
__global__ __launch_bounds__(256) void k_xh(const float* __restrict__ x,
                                            unsigned* __restrict__ A1u,
                                            unsigned* __restrict__ x8u,
                                            const int* __restrict__ dst,
                                            unsigned* __restrict__ gh){
  int bid = blockIdx.x;
  if (bid < NBBLK){
    __shared__ unsigned h[NB2];
    for (int t = threadIdx.x; t < NB2; t += 256) h[t] = 0;
    __syncthreads();
    int base = bid * CHUNK;
    for (int j = threadIdx.x; j < CHUNK; j += 256)
      atomicAdd(&h[dst[base + j] >> 10], 1u);
    __syncthreads();
    for (int t = threadIdx.x; t < NB2; t += 256) gh[bid * NB2 + t] = h[t];
    return;
  }
  int i = (bid - NBBLK) * 256 + threadIdx.x;   // over N*32 float4s
  if (i >= NNODE * 32) return;
  float4 v = ((const float4*)x)[i];
  int e = i * 4;
  int row = e >> 7, c = e & 127;
  unsigned* d = A1u + (size_t)row * 128 + 64 + (c >> 1);
  d[0] = pk2(v.x, v.y);
  d[1] = pk2(v.z, v.w);
  unsigned p = (unsigned)__builtin_amdgcn_cvt_pk_fp8_f32(v.x, v.y, 0, false);
  p = (unsigned)__builtin_amdgcn_cvt_pk_fp8_f32(v.z, v.w, (int)p, true);
  x8u[(size_t)row * 32 + (c >> 2)] = p;
}

// ---------------- CSR build: deterministic 2-pass binning ----------------
__global__ __launch_bounds__(512) void k_scan512(const unsigned* __restrict__ gh,
                                                 unsigned* __restrict__ gbase,
                                                 unsigned* __restrict__ btot){
  int b = blockIdx.x, t = threadIdx.x;
  int lane = t & 63, wv = t >> 6;
  unsigned v = gh[t * NB2 + b];
  unsigned s = v;
  #pragma unroll
  for (int off = 1; off < 64; off <<= 1){
    unsigned u = __shfl_up(s, off, 64);
    if (lane >= off) s += u;
  }
  __shared__ unsigned wsum[8];
  if (lane == 63) wsum[wv] = s;
  __syncthreads();
  unsigned woff = 0;
  for (int w = 0; w < wv; ++w) woff += wsum[w];
  gbase[t * NB2 + b] = woff + s - v;
  if (t == 511) btot[b] = woff + s;
}

__global__ __launch_bounds__(128) void k_scanb(const unsigned* __restrict__ btot,
                                               unsigned* __restrict__ bbase,
                                               unsigned* __restrict__ rowptr){
  __shared__ unsigned buf[128];
  int tid = threadIdx.x;
  unsigned v = (tid < NB2) ? btot[tid] : 0u;
  buf[tid] = v;
  __syncthreads();
  #pragma unroll
  for (int off = 1; off < 128; off <<= 1){
    unsigned t = (tid >= off) ? buf[tid - off] : 0u;
    __syncthreads();
    buf[tid] += t;
    __syncthreads();
  }
  if (tid < NB2) bbase[tid] = buf[tid] - v;
  if (tid == 0){ bbase[NB2] = NEDGE; rowptr[NNODE] = NEDGE; }
}

__global__ __launch_bounds__(256) void k_binscat(const int* __restrict__ src,
                                                 const int* __restrict__ dst,
                                                 const unsigned* __restrict__ gbase,
                                                 const unsigned* __restrict__ bbase,
                                                 unsigned* __restrict__ pairs){
  __shared__ unsigned cur[NB2];
  for (int t = threadIdx.x; t < NB2; t += 256)
    cur[t] = bbase[t] + gbase[blockIdx.x * NB2 + t];
  __syncthreads();
  int base = blockIdx.x * CHUNK;
  for (int j = threadIdx.x; j < CHUNK; j += 256){
    int s = src[base + j], d = dst[base + j];
    unsigned p = atomicAdd(&cur[d >> 10], 1u);
    pairs[p] = ((unsigned)s << 10) | (unsigned)(d & 1023);
  }
}

__global__ __launch_bounds__(1024) void k_buildcsr(const unsigned* __restrict__ bbase,
                                                   const unsigned* __restrict__ pairs,
                                                   unsigned* __restrict__ rowptr,
                                                   unsigned* __restrict__ col){
  __shared__ unsigned hist[1024];
  __shared__ unsigned wsum[16];
  const int b = blockIdx.x, tid = threadIdx.x;
  const int lane = tid & 63, wv = tid >> 6;
  const unsigned e0 = bbase[b], e1 = bbase[b + 1];
  const int nb0 = b << 10;
  hist[tid] = 0;
  __syncthreads();
  for (unsigned j = e0 + tid; j < e1; j += 1024)
    atomicAdd(&hist[pairs[j] & 1023u], 1u);
  __syncthreads();
  unsigned v = hist[tid];
  unsigned s = v;
  #pragma unroll
  for (int off = 1; off < 64; off <<= 1){
    unsigned u = __shfl_up(s, off, 64);
    if (lane >= off) s += u;
  }
  if (lane == 63) wsum[wv] = s;
  __syncthreads();
  unsigned woff = 0;
  for (int w = 0; w < wv; ++w) woff += wsum[w];
  unsigned gpos = e0 + woff + s - v;
  if (nb0 + tid < NNODE) rowptr[nb0 + tid] = gpos;
  __syncthreads();
  hist[tid] = gpos;
  __syncthreads();
  for (unsigned j = e0 + tid; j < e1; j += 1024){
    unsigned e = pairs[j];
    unsigned p = atomicAdd(&hist[e & 1023u], 1u);
    col[p] = e >> 10;
  }
}

// ---------------- fused weight conversions ----------------
__global__ void k_wcvt(const float* __restrict__ W1l, const float* __restrict__ W1r,
                       const float* __restrict__ W2l, const float* __restrict__ W2r,
                       unsigned short* __restrict__ Bwt1, unsigned short* __restrict__ Bwt2){
  int i = blockIdx.x * 256 + threadIdx.x;
  if (i < 256 * 256){
    int n = i >> 8, k = i & 255;
    float v = (k < 128) ? W1l[n * 128 + k] : W1r[n * 128 + (k - 128)];
    Bwt1[i] = f2bf(v);
  }
  int i2 = i - 256 * 256;
  if (i2 >= 0 && i2 < 128 * 256){
    int n = i2 >> 8, k = i2 & 255;
    float v = (n < 64) ? W2l[n * 256 + k] : W2r[(n - 64) * 256 + k];
    Bwt2[i2] = f2bf(v);
  }
}

// ---------------- layer-1 aggregation: 8-lane groups, uint4 fp8 loads ----------------
// one wave per node; 8 edges/iter; lane (l&7) holds dims 16u..16u+15
__global__ __launch_bounds__(256) void k_agg1(const unsigned* __restrict__ rowptr,
                                              const unsigned* __restrict__ col,
                                              const unsigned* __restrict__ x8u,
                                              unsigned* __restrict__ A1u){
  int gw = (blockIdx.x * 256 + threadIdx.x) >> 6;
  int lane = threadIdx.x & 63;
  if (gw >= NNODE) return;
  unsigned s0 = rowptr[gw], s1 = rowptr[gw + 1];
  const int sel = lane >> 3, u = lane & 7;
  const uint4* x84 = (const uint4*)x8u;   // 8 uint4 per row
  f32x2 A0={0,0},A1={0,0},A2={0,0},A3={0,0},A4={0,0},A5={0,0},A6={0,0},A7={0,0};
  unsigned j = s0;
  for (; j + 7 < s1; j += 8){
    unsigned ca = col[j + sel];
    uint4 va = x84[(size_t)ca * 8 + u];
    A0 += __builtin_amdgcn_cvt_pk_f32_fp8((int)va.x, false);
    A1 += __builtin_amdgcn_cvt_pk_f32_fp8((int)va.x, true );
    A2 += __builtin_amdgcn_cvt_pk_f32_fp8((int)va.y, false);
    A3 += __builtin_amdgcn_cvt_pk_f32_fp8((int)va.y, true );
    A4 += __builtin_amdgcn_cvt_pk_f32_fp8((int)va.z, false);
    A5 += __builtin_amdgcn_cvt_pk_f32_fp8((int)va.z, true );
    A6 += __builtin_amdgcn_cvt_pk_f32_fp8((int)va.w, false);
    A7 += __builtin_amdgcn_cvt_pk_f32_fp8((int)va.w, true );
  }
  int rem = (int)(s1 - j);
  if (sel < rem){
    unsigned ca = col[j + sel];
    uint4 va = x84[(size_t)ca * 8 + u];
    A0 += __builtin_amdgcn_cvt_pk_f32_fp8((int)va.x, false);
    A1 += __builtin_amdgcn_cvt_pk_f32_fp8((int)va.x, true );
    A2 += __builtin_amdgcn_cvt_pk_f32_fp8((int)va.y, false);
    A3 += __builtin_amdgcn_cvt_pk_f32_fp8((int)va.y, true );
    A4 += __builtin_amdgcn_cvt_pk_f32_fp8((int)va.z, false);
    A5 += __builtin_amdgcn_cvt_pk_f32_fp8((int)va.z, true );
    A6 += __builtin_amdgcn_cvt_pk_f32_fp8((int)va.w, false);
    A7 += __builtin_amdgcn_cvt_pk_f32_fp8((int)va.w, true );
  }
  #pragma unroll
  for (int mask = 8; mask <= 32; mask <<= 1){
    A0.x += __shfl_xor(A0.x, mask, 64); A0.y += __shfl_xor(A0.y, mask, 64);
    A1.x += __shfl_xor(A1.x, mask, 64); A1.y += __shfl_xor(A1.y, mask, 64);
    A2.x += __shfl_xor(A2.x, mask, 64); A2.y += __shfl_xor(A2.y, mask, 64);
    A3.x += __shfl_xor(A3.x, mask, 64); A3.y += __shfl_xor(A3.y, mask, 64);
    A4.x += __shfl_xor(A4.x, mask, 64); A4.y += __shfl_xor(A4.y, mask, 64);
    A5.x += __shfl_xor(A5.x, mask, 64); A5.y += __shfl_xor(A5.y, mask, 64);
    A6.x += __shfl_xor(A6.x, mask, 64); A6.y += __shfl_xor(A6.y, mask, 64);
    A7.x += __shfl_xor(A7.x, mask, 64); A7.y += __shfl_xor(A7.y, mask, 64);
  }
  if (lane < 8){
    float inv = 1.f / fmaxf((float)(s1 - s0), 1.f);
    uint4 w0, w1;
    w0.x = pk2(A0.x * inv, A0.y * inv);
    w0.y = pk2(A1.x * inv, A1.y * inv);
    w0.z = pk2(A2.x * inv, A2.y * inv);
    w0.w = pk2(A3.x * inv, A3.y * inv);
    w1.x = pk2(A4.x * inv, A4.y * inv);
    w1.y = pk2(A5.x * inv, A5.y * inv);
    w1.z = pk2(A6.x * inv, A6.y * inv);
    w1.w = pk2(A7.x * inv, A7.y * inv);
    unsigned* d = A1u + (size_t)gw * 128 + 8 * lane;
    *(uint4*)d = w0;
    *(uint4*)(d + 4) = w1;
  }
}

// ---------------- MFMA GEMM; MODE 0: bf16 C ; MODE 2: z8 (fp8) + r16 (bf16) split ----------------
template<int BN, bool RELU, bool BIAS, int MODE>
__global__ __launch_bounds__(256) void k_gemm(const unsigned short* __restrict__ A,
                                              const unsigned short* __restrict__ B,
                                              const float* __restrict__ bias,
                                              unsigned short* __restrict__ C,
                                              unsigned char* __restrict__ z8,
                                              unsigned short* __restrict__ r16,
                                              int nrows){
  constexpr int NF = BN / 64;
  __shared__ unsigned short a_t[64 * 64];
  __shared__ unsigned short b_t[BN * 64];
  const int tid = threadIdx.x, wave = tid >> 6, lane = tid & 63;
  const int row0 = blockIdx.x * 64;
  char* ab = (char*)a_t;
  char* bb = (char*)b_t;

  f32x4 acc[4][NF];
  #pragma unroll
  for (int m = 0; m < 4; ++m)
    #pragma unroll
    for (int n = 0; n < NF; ++n)
      acc[m][n] = (f32x4){0.f, 0.f, 0.f, 0.f};

  for (int kt = 0; kt < 4; ++kt){
    {
      int r = tid >> 2;
      int gr = row0 + r; if (gr > nrows - 1) gr = nrows - 1;
      const uint4* s4 = (const uint4*)(A + (size_t)gr * 256 + kt * 64);
      int c0 = (tid & 3) * 2;
      uint4 v0 = s4[c0], v1 = s4[c0 + 1];
      *(uint4*)(ab + r * 128 + ((c0 * 16) ^ ((r & 7) << 4))) = v0;
      *(uint4*)(ab + r * 128 + (((c0 + 1) * 16) ^ ((r & 7) << 4))) = v1;
    }
    {
      constexpr int CPT = BN / 32;
      #pragma unroll
      for (int c = 0; c < CPT; ++c){
        int gc = tid * CPT + c;
        int n = gc >> 3, ck = gc & 7;
        uint4 v = ((const uint4*)(B + (size_t)n * 256 + kt * 64))[ck];
        *(uint4*)(bb + n * 128 + ((ck * 16) ^ ((n & 7) << 4))) = v;
      }
    }
    __syncthreads();
    #pragma unroll
    for (int kk = 0; kk < 2; ++kk){
      int k2 = (kk * 32 + ((lane >> 4) * 8)) * 2;
      bf16x8 af[4];
      #pragma unroll
      for (int m = 0; m < 4; ++m){
        int rr = m * 16 + (lane & 15);
        af[m] = *(const bf16x8*)(ab + rr * 128 + (k2 ^ ((rr & 7) << 4)));
      }
      #pragma unroll
      for (int n = 0; n < NF; ++n){
        int cc = wave * (16 * NF) + n * 16 + (lane & 15);
        bf16x8 bfv = *(const bf16x8*)(bb + cc * 128 + (k2 ^ ((cc & 7) << 4)));
        #pragma unroll
        for (int m = 0; m < 4; ++m)
          acc[m][n] = __builtin_amdgcn_mfma_f32_16x16x32_bf16(af[m], bfv, acc[m][n], 0, 0, 0);
      }
    }
    __syncthreads();
  }
  #pragma unroll
  for (int m = 0; m < 4; ++m){
    int rbase = row0 + m * 16 + ((lane >> 4) << 2);
    #pragma unroll
    for (int r = 0; r < 4; ++r){
      if (rbase + r < nrows){
        #pragma unroll
        for (int n = 0; n < NF; ++n){
          int cc = wave * (16 * NF) + n * 16 + (lane & 15);
          float v = acc[m][n][r];
          if (BIAS) v += bias[cc];
          if (RELU) v = fmaxf(v, 0.f);
          if (MODE == 0){
            C[(size_t)(rbase + r) * BN + cc] = f2bf(v);
          } else {
            if (cc < 64)
              z8[(size_t)(rbase + r) * 64 + cc] =
                (unsigned char)__builtin_amdgcn_cvt_pk_fp8_f32(v, v, 0, false);
            else
              r16[(size_t)(rbase + r) * 64 + (cc - 64)] = f2bf(v);
          }
        }
      }
    }
  }
}

// ---------------- layer-2 aggregation: 8-lane groups, uint2 fp8 loads + residual + bias ----------------
// one wave per node; lane (l&7) holds dims 8u..8u+7
__global__ __launch_bounds__(256) void k_agg2(const unsigned* __restrict__ rowptr,
                                              const unsigned* __restrict__ col,
                                              const unsigned* __restrict__ z8u,
                                              const unsigned* __restrict__ r16u,
                                              const float* __restrict__ b2,
                                              float* __restrict__ out){
  int gw = (blockIdx.x * 256 + threadIdx.x) >> 6;
  int lane = threadIdx.x & 63;
  if (gw >= NNODE) return;
  unsigned s0 = rowptr[gw], s1 = rowptr[gw + 1];
  const int sel = lane >> 3, u = lane & 7;
  const uint2* z82 = (const uint2*)z8u;   // 8 uint2 per row
  f32x2 A0={0,0},A1={0,0},A2={0,0},A3={0,0};
  unsigned j = s0;
  for (; j + 7 < s1; j += 8){
    unsigned ca = col[j + sel];
    uint2 va = z82[(size_t)ca * 8 + u];
    A0 += __builtin_amdgcn_cvt_pk_f32_fp8((int)va.x, false);
    A1 += __builtin_amdgcn_cvt_pk_f32_fp8((int)va.x, true );
    A2 += __builtin_amdgcn_cvt_pk_f32_fp8((int)va.y, false);
    A3 += __builtin_amdgcn_cvt_pk_f32_fp8((int)va.y, true );
  }
  int rem = (int)(s1 - j);
  if (sel < rem){
    unsigned ca = col[j + sel];
    uint2 va = z82[(size_t)ca * 8 + u];
    A0 += __builtin_amdgcn_cvt_pk_f32_fp8((int)va.x, false);
    A1 += __builtin_amdgcn_cvt_pk_f32_fp8((int)va.x, true );
    A2 += __builtin_amdgcn_cvt_pk_f32_fp8((int)va.y, false);
    A3 += __builtin_amdgcn_cvt_pk_f32_fp8((int)va.y, true );
  }
  #pragma unroll
  for (int mask = 8; mask <= 32; mask <<= 1){
    A0.x += __shfl_xor(A0.x, mask, 64); A0.y += __shfl_xor(A0.y, mask, 64);
    A1.x += __shfl_xor(A1.x, mask, 64); A1.y += __shfl_xor(A1.y, mask, 64);
    A2.x += __shfl_xor(A2.x, mask, 64); A2.y += __shfl_xor(A2.y, mask, 64);
    A3.x += __shfl_xor(A3.x, mask, 64); A3.y += __shfl_xor(A3.y, mask, 64);
  }
  if (lane < 8){
    float inv = 1.f / fmaxf((float)(s1 - s0), 1.f);
    uint4 rv = ((const uint4*)(r16u + (size_t)gw * 32))[lane];
    float4 b0 = ((const float4*)b2)[2 * lane];
    float4 b1 = ((const float4*)b2)[2 * lane + 1];
    float4 o0, o1;
    o0.x = A0.x * inv + bflo(rv.x) + b0.x;
    o0.y = A0.y * inv + bfhi(rv.x) + b0.y;
    o0.z = A1.x * inv + bflo(rv.y) + b0.z;
    o0.w = A1.y * inv + bfhi(rv.y) + b0.w;
    o1.x = A2.x * inv + bflo(rv.z) + b1.x;
    o1.y = A2.y * inv + bfhi(rv.z) + b1.y;
    o1.z = A3.x * inv + bflo(rv.w) + b1.z;
    o1.w = A3.y * inv + bfhi(rv.w) + b1.w;
    ((float4*)out)[(size_t)gw * 16 + 2 * lane] = o0;
    ((float4*)out)[(size_t)gw * 16 + 2 * lane + 1] = o1;
  }
}

extern "C" void kernel_launch(void* const* d_in, const int* in_sizes, int n_in,
                              void* d_out, int out_size, void* d_ws, size_t ws_size,
                              hipStream_t stream) {
  const float* x   = (const float*)d_in[0];
  const int*   ei  = (const int*)d_in[1];
  const float* W1l = (const float*)d_in[2];
  const float* b1  = (const float*)d_in[3];
  const float* W1r = (const float*)d_in[4];
  const float* W2l = (const float*)d_in[5];
  const float* b2  = (const float*)d_in[6];
  const float* W2r = (const float*)d_in[7];
  float* out = (float*)d_out;

  char* ws = (char*)d_ws;
  size_t off = 0;
  auto alloc = [&](size_t bytes) -> void* {
    void* p = ws + off;
    off = (off + bytes + 255) & ~(size_t)255;
    return p;
  };
  unsigned* rowptr = (unsigned*)alloc((size_t)(NNODE + 1) * 4);
  unsigned* col    = (unsigned*)alloc((size_t)NEDGE * 4);
  unsigned* pairs  = (unsigned*)alloc((size_t)NEDGE * 4);
  unsigned* gh     = (unsigned*)alloc((size_t)NBBLK * NB2 * 4);
  unsigned* gbase  = (unsigned*)alloc((size_t)NBBLK * NB2 * 4);
  unsigned* btot   = (unsigned*)alloc((size_t)NB2 * 4);
  unsigned* bbase  = (unsigned*)alloc((size_t)(NB2 + 1) * 4);
  unsigned short* A1   = (unsigned short*)alloc((size_t)NNODE * 256 * 2);
  unsigned short* h    = (unsigned short*)alloc((size_t)NNODE * 256 * 2);
  unsigned short* r16  = (unsigned short*)alloc((size_t)NNODE * 64 * 2);
  unsigned* x8u        = (unsigned*)alloc((size_t)NNODE * 32 * 4);
  unsigned char* z8    = (unsigned char*)alloc((size_t)NNODE * 64);
  unsigned short* Bwt1 = (unsigned short*)alloc(256 * 256 * 2);
  unsigned short* Bwt2 = (unsigned short*)alloc(128 * 256 * 2);

  const int* srcv = ei;
  const int* dstv = ei + NEDGE;

  k_xh<<<NBBLK + (NNODE * 32 + 255) / 256, 256, 0, stream>>>(x, (unsigned*)A1, x8u, dstv, gh);
  k_scan512<<<NB2, 512, 0, stream>>>(gh, gbase, btot);
  k_scanb<<<1, 128, 0, stream>>>(btot, bbase, rowptr);
  k_binscat<<<NBBLK, 256, 0, stream>>>(srcv, dstv, gbase, bbase, pairs);
  k_buildcsr<<<NB2, 1024, 0, stream>>>(bbase, pairs, rowptr, col);

  k_wcvt<<<(256 * 256 + 128 * 256 + 255) / 256, 256, 0, stream>>>(W1l, W1r, W2l, W2r, Bwt1, Bwt2);

  k_agg1<<<(NNODE + 3) / 4, 256, 0, stream>>>(rowptr, col, x8u, (unsigned*)A1);

  int gblocks = (NNODE + 63) / 64;
  k_gemm<256, true,  true,  0><<<gblocks, 256, 0, stream>>>(A1, Bwt1, b1, h, nullptr, nullptr, NNODE);
  k_gemm<128, false, false, 2><<<gblocks, 256, 0, stream>>>(h,  Bwt2, nullptr, nullptr, z8, r16, NNODE);

  k_agg2<<<(NNODE + 3) / 4, 256, 0, stream>>>(rowptr, col, (const unsigned*)z8, (const unsigned*)r16, b2, out);
}

// Round 8
// 314.194 us; speedup vs baseline: 1.6565x; 1.0143x over previous
//
#include <hip/hip_runtime.h>
#include <hip/hip_bf16.h>

#define NNODE 100000
#define NEDGE 1600000
#define NBBLK 512
#define CHUNK (NEDGE / NBBLK)              // 3125 edges per binning block
#define NB2 ((NNODE + 1023) >> 10)         // 98 buckets of 1024 dst-nodes

typedef __attribute__((ext_vector_type(8))) short bf16x8;
typedef __attribute__((ext_vector_type(4))) float f32x4;
typedef __attribute__((ext_vector_type(2))) float f32x2;

__device__ __forceinline__ unsigned short f2bf(float f){
  unsigned u = __float_as_uint(f);
  u += 0x7fffu + ((u >> 16) & 1u);
  return (unsigned short)(u >> 16);
}
__device__ __forceinline__ unsigned pk2(float a, float b){
  return (unsigned)f2bf(a) | ((unsigned)f2bf(b) << 16);
}
__device__ __forceinline__ float bflo(unsigned v){ return __uint_as_float(v << 16); }
__device__ __forceinline__ float bfhi(unsigned v){ return __uint_as_float(v & 0xffff0000u); }

// ---------------- fused: x conversion (bf16 + fp8) AND edge histogram ----------------
__global__ __launch_bounds__(256) void k_xh(const float* __restrict__ x,
                                            unsigned* __restrict__ A1u,
                                            unsigned* __restrict__ x8u,
                                            const int* __restrict__ dst,
                                            unsigned* __restrict__ gh){
  int bid = blockIdx.x;
  if (bid < NBBLK){
    __shared__ unsigned h[NB2];
    for (int t = threadIdx.x; t < NB2; t += 256) h[t] = 0;
    __syncthreads();
    int base = bid * CHUNK;
    for (int j = threadIdx.x; j < CHUNK; j += 256)
      atomicAdd(&h[dst[base + j] >> 10], 1u);
    __syncthreads();
    for (int t = threadIdx.x; t < NB2; t += 256) gh[bid * NB2 + t] = h[t];
    return;
  }
  int i = (bid - NBBLK) * 256 + threadIdx.x;   // over N*32 float4s
  if (i >= NNODE * 32) return;
  float4 v = ((const float4*)x)[i];
  int e = i * 4;
  int row = e >> 7, c = e & 127;
  unsigned* d = A1u + (size_t)row * 128 + 64 + (c >> 1);
  d[0] = pk2(v.x, v.y);
  d[1] = pk2(v.z, v.w);
  unsigned p = (unsigned)__builtin_amdgcn_cvt_pk_fp8_f32(v.x, v.y, 0, false);
  p = (unsigned)__builtin_amdgcn_cvt_pk_fp8_f32(v.z, v.w, (int)p, true);
  x8u[(size_t)row * 32 + (c >> 2)] = p;
}

// ---------------- CSR build: deterministic 2-pass binning ----------------
__global__ __launch_bounds__(512) void k_scan512(const unsigned* __restrict__ gh,
                                                 unsigned* __restrict__ gbase,
                                                 unsigned* __restrict__ btot){
  int b = blockIdx.x, t = threadIdx.x;
  int lane = t & 63, wv = t >> 6;
  unsigned v = gh[t * NB2 + b];
  unsigned s = v;
  #pragma unroll
  for (int off = 1; off < 64; off <<= 1){
    unsigned u = __shfl_up(s, off, 64);
    if (lane >= off) s += u;
  }
  __shared__ unsigned wsum[8];
  if (lane == 63) wsum[wv] = s;
  __syncthreads();
  unsigned woff = 0;
  for (int w = 0; w < wv; ++w) woff += wsum[w];
  gbase[t * NB2 + b] = woff + s - v;
  if (t == 511) btot[b] = woff + s;
}

__global__ __launch_bounds__(128) void k_scanb(const unsigned* __restrict__ btot,
                                               unsigned* __restrict__ bbase,
                                               unsigned* __restrict__ rowptr){
  __shared__ unsigned buf[128];
  int tid = threadIdx.x;
  unsigned v = (tid < NB2) ? btot[tid] : 0u;
  buf[tid] = v;
  __syncthreads();
  #pragma unroll
  for (int off = 1; off < 128; off <<= 1){
    unsigned t = (tid >= off) ? buf[tid - off] : 0u;
    __syncthreads();
    buf[tid] += t;
    __syncthreads();
  }
  if (tid < NB2) bbase[tid] = buf[tid] - v;
  if (tid == 0){ bbase[NB2] = NEDGE; rowptr[NNODE] = NEDGE; }
}

__global__ __launch_bounds__(256) void k_binscat(const int* __restrict__ src,
                                                 const int* __restrict__ dst,
                                                 const unsigned* __restrict__ gbase,
                                                 const unsigned* __restrict__ bbase,
                                                 unsigned* __restrict__ pairs){
  __shared__ unsigned cur[NB2];
  for (int t = threadIdx.x; t < NB2; t += 256)
    cur[t] = bbase[t] + gbase[blockIdx.x * NB2 + t];
  __syncthreads();
  int base = blockIdx.x * CHUNK;
  for (int j = threadIdx.x; j < CHUNK; j += 256){
    int s = src[base + j], d = dst[base + j];
    unsigned p = atomicAdd(&cur[d >> 10], 1u);
    pairs[p] = ((unsigned)s << 10) | (unsigned)(d & 1023);
  }
}

__global__ __launch_bounds__(1024) void k_buildcsr(const unsigned* __restrict__ bbase,
                                                   const unsigned* __restrict__ pairs,
                                                   unsigned* __restrict__ rowptr,
                                                   unsigned* __restrict__ col){
  __shared__ unsigned hist[1024];
  __shared__ unsigned wsum[16];
  const int b = blockIdx.x, tid = threadIdx.x;
  const int lane = tid & 63, wv = tid >> 6;
  const unsigned e0 = bbase[b], e1 = bbase[b + 1];
  const int nb0 = b << 10;
  hist[tid] = 0;
  __syncthreads();
  for (unsigned j = e0 + tid; j < e1; j += 1024)
    atomicAdd(&hist[pairs[j] & 1023u], 1u);
  __syncthreads();
  unsigned v = hist[tid];
  unsigned s = v;
  #pragma unroll
  for (int off = 1; off < 64; off <<= 1){
    unsigned u = __shfl_up(s, off, 64);
    if (lane >= off) s += u;
  }
  if (lane == 63) wsum[wv] = s;
  __syncthreads();
  unsigned woff = 0;
  for (int w = 0; w < wv; ++w) woff += wsum[w];
  unsigned gpos = e0 + woff + s - v;
  if (nb0 + tid < NNODE) rowptr[nb0 + tid] = gpos;
  __syncthreads();
  hist[tid] = gpos;
  __syncthreads();
  for (unsigned j = e0 + tid; j < e1; j += 1024){
    unsigned e = pairs[j];
    unsigned p = atomicAdd(&hist[e & 1023u], 1u);
    col[p] = e >> 10;
  }
}

// ---------------- fused weight conversions ----------------
__global__ void k_wcvt(const float* __restrict__ W1l, const float* __restrict__ W1r,
                       const float* __restrict__ W2l, const float* __restrict__ W2r,
                       unsigned short* __restrict__ Bwt1, unsigned short* __restrict__ Bwt2){
  int i = blockIdx.x * 256 + threadIdx.x;
  if (i < 256 * 256){
    int n = i >> 8, k = i & 255;
    float v = (k < 128) ? W1l[n * 128 + k] : W1r[n * 128 + (k - 128)];
    Bwt1[i] = f2bf(v);
  }
  int i2 = i - 256 * 256;
  if (i2 >= 0 && i2 < 128 * 256){
    int n = i2 >> 8, k = i2 & 255;
    float v = (n < 64) ? W2l[n * 256 + k] : W2r[(n - 64) * 256 + k];
    Bwt2[i2] = f2bf(v);
  }
}

// ---------------- layer-1 aggregation: 16-lane groups, 4 gathers in flight ----------------
// one wave per node; lane (l&15) holds dims 8u..8u+7 via uint2 (fp8 row = 128B)
__global__ __launch_bounds__(256) void k_agg1(const unsigned* __restrict__ rowptr,
                                              const unsigned* __restrict__ col,
                                              const unsigned* __restrict__ x8u,
                                              unsigned* __restrict__ A1u){
  int gw = (blockIdx.x * 256 + threadIdx.x) >> 6;
  int lane = threadIdx.x & 63;
  if (gw >= NNODE) return;
  unsigned s0 = rowptr[gw], s1 = rowptr[gw + 1];
  const int sel = lane >> 4, u = lane & 15;
  const uint2* x82 = (const uint2*)x8u;   // 16 uint2 per row
  float a0=0.f,a1=0.f,a2=0.f,a3=0.f,a4=0.f,a5=0.f,a6=0.f,a7=0.f;
  f32x2 p;
  unsigned j = s0;
  for (; j + 15 < s1; j += 16){
    unsigned ca = col[j + sel], cb = col[j + 4 + sel];
    unsigned cc = col[j + 8 + sel], cd = col[j + 12 + sel];
    uint2 va = x82[(size_t)ca * 16 + u];
    uint2 vb = x82[(size_t)cb * 16 + u];
    uint2 vc = x82[(size_t)cc * 16 + u];
    uint2 vd = x82[(size_t)cd * 16 + u];
    p = __builtin_amdgcn_cvt_pk_f32_fp8((int)va.x, false); a0+=p.x; a1+=p.y;
    p = __builtin_amdgcn_cvt_pk_f32_fp8((int)va.x, true ); a2+=p.x; a3+=p.y;
    p = __builtin_amdgcn_cvt_pk_f32_fp8((int)va.y, false); a4+=p.x; a5+=p.y;
    p = __builtin_amdgcn_cvt_pk_f32_fp8((int)va.y, true ); a6+=p.x; a7+=p.y;
    p = __builtin_amdgcn_cvt_pk_f32_fp8((int)vb.x, false); a0+=p.x; a1+=p.y;
    p = __builtin_amdgcn_cvt_pk_f32_fp8((int)vb.x, true ); a2+=p.x; a3+=p.y;
    p = __builtin_amdgcn_cvt_pk_f32_fp8((int)vb.y, false); a4+=p.x; a5+=p.y;
    p = __builtin_amdgcn_cvt_pk_f32_fp8((int)vb.y, true ); a6+=p.x; a7+=p.y;
    p = __builtin_amdgcn_cvt_pk_f32_fp8((int)vc.x, false); a0+=p.x; a1+=p.y;
    p = __builtin_amdgcn_cvt_pk_f32_fp8((int)vc.x, true ); a2+=p.x; a3+=p.y;
    p = __builtin_amdgcn_cvt_pk_f32_fp8((int)vc.y, false); a4+=p.x; a5+=p.y;
    p = __builtin_amdgcn_cvt_pk_f32_fp8((int)vc.y, true ); a6+=p.x; a7+=p.y;
    p = __builtin_amdgcn_cvt_pk_f32_fp8((int)vd.x, false); a0+=p.x; a1+=p.y;
    p = __builtin_amdgcn_cvt_pk_f32_fp8((int)vd.x, true ); a2+=p.x; a3+=p.y;
    p = __builtin_amdgcn_cvt_pk_f32_fp8((int)vd.y, false); a4+=p.x; a5+=p.y;
    p = __builtin_amdgcn_cvt_pk_f32_fp8((int)vd.y, true ); a6+=p.x; a7+=p.y;
  }
  for (; j + 3 < s1; j += 4){
    unsigned ca = col[j + sel];
    uint2 va = x82[(size_t)ca * 16 + u];
    p = __builtin_amdgcn_cvt_pk_f32_fp8((int)va.x, false); a0+=p.x; a1+=p.y;
    p = __builtin_amdgcn_cvt_pk_f32_fp8((int)va.x, true ); a2+=p.x; a3+=p.y;
    p = __builtin_amdgcn_cvt_pk_f32_fp8((int)va.y, false); a4+=p.x; a5+=p.y;
    p = __builtin_amdgcn_cvt_pk_f32_fp8((int)va.y, true ); a6+=p.x; a7+=p.y;
  }
  int rem = (int)(s1 - j);
  if (sel < rem){
    unsigned ca = col[j + sel];
    uint2 va = x82[(size_t)ca * 16 + u];
    p = __builtin_amdgcn_cvt_pk_f32_fp8((int)va.x, false); a0+=p.x; a1+=p.y;
    p = __builtin_amdgcn_cvt_pk_f32_fp8((int)va.x, true ); a2+=p.x; a3+=p.y;
    p = __builtin_amdgcn_cvt_pk_f32_fp8((int)va.y, false); a4+=p.x; a5+=p.y;
    p = __builtin_amdgcn_cvt_pk_f32_fp8((int)va.y, true ); a6+=p.x; a7+=p.y;
  }
  // reduce the 4 edge-groups (lanes differing in bits 4,5)
  a0 += __shfl_xor(a0, 16, 64); a1 += __shfl_xor(a1, 16, 64);
  a2 += __shfl_xor(a2, 16, 64); a3 += __shfl_xor(a3, 16, 64);
  a4 += __shfl_xor(a4, 16, 64); a5 += __shfl_xor(a5, 16, 64);
  a6 += __shfl_xor(a6, 16, 64); a7 += __shfl_xor(a7, 16, 64);
  a0 += __shfl_xor(a0, 32, 64); a1 += __shfl_xor(a1, 32, 64);
  a2 += __shfl_xor(a2, 32, 64); a3 += __shfl_xor(a3, 32, 64);
  a4 += __shfl_xor(a4, 32, 64); a5 += __shfl_xor(a5, 32, 64);
  a6 += __shfl_xor(a6, 32, 64); a7 += __shfl_xor(a7, 32, 64);
  if (lane < 16){
    float inv = 1.f / fmaxf((float)(s1 - s0), 1.f);
    uint4 w;
    w.x = pk2(a0 * inv, a1 * inv);
    w.y = pk2(a2 * inv, a3 * inv);
    w.z = pk2(a4 * inv, a5 * inv);
    w.w = pk2(a6 * inv, a7 * inv);
    *(uint4*)(A1u + (size_t)gw * 128 + 4 * lane) = w;
  }
}

// ---------------- MFMA GEMM; MODE 0: bf16 C ; MODE 2: z8 (fp8) + r16 (bf16) split ----------------
template<int BN, bool RELU, bool BIAS, int MODE>
__global__ __launch_bounds__(256) void k_gemm(const unsigned short* __restrict__ A,
                                              const unsigned short* __restrict__ B,
                                              const float* __restrict__ bias,
                                              unsigned short* __restrict__ C,
                                              unsigned char* __restrict__ z8,
                                              unsigned short* __restrict__ r16,
                                              int nrows){
  constexpr int NF = BN / 64;
  __shared__ unsigned short a_t[64 * 64];
  __shared__ unsigned short b_t[BN * 64];
  const int tid = threadIdx.x, wave = tid >> 6, lane = tid & 63;
  const int row0 = blockIdx.x * 64;
  char* ab = (char*)a_t;
  char* bb = (char*)b_t;

  f32x4 acc[4][NF];
  #pragma unroll
  for (int m = 0; m < 4; ++m)
    #pragma unroll
    for (int n = 0; n < NF; ++n)
      acc[m][n] = (f32x4){0.f, 0.f, 0.f, 0.f};

  for (int kt = 0; kt < 4; ++kt){
    {
      int r = tid >> 2;
      int gr = row0 + r; if (gr > nrows - 1) gr = nrows - 1;
      const uint4* s4 = (const uint4*)(A + (size_t)gr * 256 + kt * 64);
      int c0 = (tid & 3) * 2;
      uint4 v0 = s4[c0], v1 = s4[c0 + 1];
      *(uint4*)(ab + r * 128 + ((c0 * 16) ^ ((r & 7) << 4))) = v0;
      *(uint4*)(ab + r * 128 + (((c0 + 1) * 16) ^ ((r & 7) << 4))) = v1;
    }
    {
      constexpr int CPT = BN / 32;
      #pragma unroll
      for (int c = 0; c < CPT; ++c){
        int gc = tid * CPT + c;
        int n = gc >> 3, ck = gc & 7;
        uint4 v = ((const uint4*)(B + (size_t)n * 256 + kt * 64))[ck];
        *(uint4*)(bb + n * 128 + ((ck * 16) ^ ((n & 7) << 4))) = v;
      }
    }
    __syncthreads();
    #pragma unroll
    for (int kk = 0; kk < 2; ++kk){
      int k2 = (kk * 32 + ((lane >> 4) * 8)) * 2;
      bf16x8 af[4];
      #pragma unroll
      for (int m = 0; m < 4; ++m){
        int rr = m * 16 + (lane & 15);
        af[m] = *(const bf16x8*)(ab + rr * 128 + (k2 ^ ((rr & 7) << 4)));
      }
      #pragma unroll
      for (int n = 0; n < NF; ++n){
        int cc = wave * (16 * NF) + n * 16 + (lane & 15);
        bf16x8 bfv = *(const bf16x8*)(bb + cc * 128 + (k2 ^ ((cc & 7) << 4)));
        #pragma unroll
        for (int m = 0; m < 4; ++m)
          acc[m][n] = __builtin_amdgcn_mfma_f32_16x16x32_bf16(af[m], bfv, acc[m][n], 0, 0, 0);
      }
    }
    __syncthreads();
  }
  #pragma unroll
  for (int m = 0; m < 4; ++m){
    int rbase = row0 + m * 16 + ((lane >> 4) << 2);
    #pragma unroll
    for (int r = 0; r < 4; ++r){
      if (rbase + r < nrows){
        #pragma unroll
        for (int n = 0; n < NF; ++n){
          int cc = wave * (16 * NF) + n * 16 + (lane & 15);
          float v = acc[m][n][r];
          if (BIAS) v += bias[cc];
          if (RELU) v = fmaxf(v, 0.f);
          if (MODE == 0){
            C[(size_t)(rbase + r) * BN + cc] = f2bf(v);
          } else {
            if (cc < 64)
              z8[(size_t)(rbase + r) * 64 + cc] =
                (unsigned char)__builtin_amdgcn_cvt_pk_fp8_f32(v, v, 0, false);
            else
              r16[(size_t)(rbase + r) * 64 + (cc - 64)] = f2bf(v);
          }
        }
      }
    }
  }
}

// ---------------- layer-2 aggregation: 16-lane groups, 4 gathers in flight ----------------
// one wave per node; lane (l&15) holds dims 4u..4u+3 via uint (fp8 row = 64B)
__global__ __launch_bounds__(256) void k_agg2(const unsigned* __restrict__ rowptr,
                                              const unsigned* __restrict__ col,
                                              const unsigned* __restrict__ z8u,
                                              const unsigned* __restrict__ r16u,
                                              const float* __restrict__ b2,
                                              float* __restrict__ out){
  int gw = (blockIdx.x * 256 + threadIdx.x) >> 6;
  int lane = threadIdx.x & 63;
  if (gw >= NNODE) return;
  unsigned s0 = rowptr[gw], s1 = rowptr[gw + 1];
  const int sel = lane >> 4, u = lane & 15;
  float a0=0.f,a1=0.f,a2=0.f,a3=0.f;
  f32x2 p;
  unsigned j = s0;
  for (; j + 15 < s1; j += 16){
    unsigned ca = col[j + sel], cb = col[j + 4 + sel];
    unsigned cc = col[j + 8 + sel], cd = col[j + 12 + sel];
    unsigned va = z8u[(size_t)ca * 16 + u];
    unsigned vb = z8u[(size_t)cb * 16 + u];
    unsigned vc = z8u[(size_t)cc * 16 + u];
    unsigned vd = z8u[(size_t)cd * 16 + u];
    p = __builtin_amdgcn_cvt_pk_f32_fp8((int)va, false); a0+=p.x; a1+=p.y;
    p = __builtin_amdgcn_cvt_pk_f32_fp8((int)va, true ); a2+=p.x; a3+=p.y;
    p = __builtin_amdgcn_cvt_pk_f32_fp8((int)vb, false); a0+=p.x; a1+=p.y;
    p = __builtin_amdgcn_cvt_pk_f32_fp8((int)vb, true ); a2+=p.x; a3+=p.y;
    p = __builtin_amdgcn_cvt_pk_f32_fp8((int)vc, false); a0+=p.x; a1+=p.y;
    p = __builtin_amdgcn_cvt_pk_f32_fp8((int)vc, true ); a2+=p.x; a3+=p.y;
    p = __builtin_amdgcn_cvt_pk_f32_fp8((int)vd, false); a0+=p.x; a1+=p.y;
    p = __builtin_amdgcn_cvt_pk_f32_fp8((int)vd, true ); a2+=p.x; a3+=p.y;
  }
  for (; j + 3 < s1; j += 4){
    unsigned ca = col[j + sel];
    unsigned va = z8u[(size_t)ca * 16 + u];
    p = __builtin_amdgcn_cvt_pk_f32_fp8((int)va, false); a0+=p.x; a1+=p.y;
    p = __builtin_amdgcn_cvt_pk_f32_fp8((int)va, true ); a2+=p.x; a3+=p.y;
  }
  int rem = (int)(s1 - j);
  if (sel < rem){
    unsigned ca = col[j + sel];
    unsigned va = z8u[(size_t)ca * 16 + u];
    p = __builtin_amdgcn_cvt_pk_f32_fp8((int)va, false); a0+=p.x; a1+=p.y;
    p = __builtin_amdgcn_cvt_pk_f32_fp8((int)va, true ); a2+=p.x; a3+=p.y;
  }
  a0 += __shfl_xor(a0, 16, 64); a1 += __shfl_xor(a1, 16, 64);
  a2 += __shfl_xor(a2, 16, 64); a3 += __shfl_xor(a3, 16, 64);
  a0 += __shfl_xor(a0, 32, 64); a1 += __shfl_xor(a1, 32, 64);
  a2 += __shfl_xor(a2, 32, 64); a3 += __shfl_xor(a3, 32, 64);
  if (lane < 16){
    float inv = 1.f / fmaxf((float)(s1 - s0), 1.f);
    uint2 rv = ((const uint2*)(r16u + (size_t)gw * 32))[lane];
    float4 bv = ((const float4*)b2)[lane];
    float4 res;
    res.x = a0 * inv + bflo(rv.x) + bv.x;
    res.y = a1 * inv + bfhi(rv.x) + bv.y;
    res.z = a2 * inv + bflo(rv.y) + bv.z;
    res.w = a3 * inv + bfhi(rv.y) + bv.w;
    ((float4*)out)[(size_t)gw * 16 + lane] = res;
  }
}

extern "C" void kernel_launch(void* const* d_in, const int* in_sizes, int n_in,
                              void* d_out, int out_size, void* d_ws, size_t ws_size,
                              hipStream_t stream) {
  const float* x   = (const float*)d_in[0];
  const int*   ei  = (const int*)d_in[1];
  const float* W1l = (const float*)d_in[2];
  const float* b1  = (const float*)d_in[3];
  const float* W1r = (const float*)d_in[4];
  const float* W2l = (const float*)d_in[5];
  const float* b2  = (const float*)d_in[6];
  const float* W2r = (const float*)d_in[7];
  float* out = (float*)d_out;

  char* ws = (char*)d_ws;
  size_t off = 0;
  auto alloc = [&](size_t bytes) -> void* {
    void* p = ws + off;
    off = (off + bytes + 255) & ~(size_t)255;
    return p;
  };
  unsigned* rowptr = (unsigned*)alloc((size_t)(NNODE + 1) * 4);
  unsigned* col    = (unsigned*)alloc((size_t)NEDGE * 4);
  unsigned* pairs  = (unsigned*)alloc((size_t)NEDGE * 4);
  unsigned* gh     = (unsigned*)alloc((size_t)NBBLK * NB2 * 4);
  unsigned* gbase  = (unsigned*)alloc((size_t)NBBLK * NB2 * 4);
  unsigned* btot   = (unsigned*)alloc((size_t)NB2 * 4);
  unsigned* bbase  = (unsigned*)alloc((size_t)(NB2 + 1) * 4);
  unsigned short* A1   = (unsigned short*)alloc((size_t)NNODE * 256 * 2);
  unsigned short* h    = (unsigned short*)alloc((size_t)NNODE * 256 * 2);
  unsigned short* r16  = (unsigned short*)alloc((size_t)NNODE * 64 * 2);
  unsigned* x8u        = (unsigned*)alloc((size_t)NNODE * 32 * 4);
  unsigned char* z8    = (unsigned char*)alloc((size_t)NNODE * 64);
  unsigned short* Bwt1 = (unsigned short*)alloc(256 * 256 * 2);
  unsigned short* Bwt2 = (unsigned short*)alloc(128 * 256 * 2);

  const int* srcv = ei;
  const int* dstv = ei + NEDGE;

  k_xh<<<NBBLK + (NNODE * 32 + 255) / 256, 256, 0, stream>>>(x, (unsigned*)A1, x8u, dstv, gh);
  k_scan512<<<NB2, 512, 0, stream>>>(gh, gbase, btot);
  k_scanb<<<1, 128, 0, stream>>>(btot, bbase, rowptr);
  k_binscat<<<NBBLK, 256, 0, stream>>>(srcv, dstv, gbase, bbase, pairs);
  k_buildcsr<<<NB2, 1024, 0, stream>>>(bbase, pairs, rowptr, col);

  k_wcvt<<<(256 * 256 + 128 * 256 + 255) / 256, 256, 0, stream>>>(W1l, W1r, W2l, W2r, Bwt1, Bwt2);

  k_agg1<<<(NNODE + 3) / 4, 256, 0, stream>>>(rowptr, col, x8u, (unsigned*)A1);

  int gblocks = (NNODE + 63) / 64;
  k_gemm<256, true,  true,  0><<<gblocks, 256, 0, stream>>>(A1, Bwt1, b1, h, nullptr, nullptr, NNODE);
  k_gemm<128, false, false, 2><<<gblocks, 256, 0, stream>>>(h,  Bwt2, nullptr, nullptr, z8, r16, NNODE);

  k_agg2<<<(NNODE + 3) / 4, 256, 0, stream>>>(rowptr, col, (const unsigned*)z8, (const unsigned*)r16, b2, out);
}

// Round 10
// 297.225 us; speedup vs baseline: 1.7510x; 1.0571x over previous
//
#include <hip/hip_runtime.h>
#include <hip/hip_bf16.h>

#define NNODE 100000
#define NEDGE 1600000
#define NBBLK 512
#define CHUNK (NEDGE / NBBLK)              // 3125 edges per binning block
#define NBUCK ((NNODE + 511) >> 9)         // 196 buckets of 512 dst-nodes
#define XB ((NNODE * 32 + 255) / 256)      // 12500 x-convert blocks
#define WB 384                             // weight-convert blocks

typedef __attribute__((ext_vector_type(8))) short bf16x8;
typedef __attribute__((ext_vector_type(4))) float f32x4;
typedef __attribute__((ext_vector_type(2))) float f32x2;

__device__ __forceinline__ unsigned short f2bf(float f){
  unsigned u = __float_as_uint(f);
  u += 0x7fffu + ((u >> 16) & 1u);
  return (unsigned short)(u >> 16);
}
__device__ __forceinline__ unsigned pk2(float a, float b){
  return (unsigned)f2bf(a) | ((unsigned)f2bf(b) << 16);
}
__device__ __forceinline__ float bflo(unsigned v){ return __uint_as_float(v << 16); }
__device__ __forceinline__ float bfhi(unsigned v){ return __uint_as_float(v & 0xffff0000u); }

// ---------------- fused: edge histogram | x conversion | weight conversion ----------------
__global__ __launch_bounds__(256) void k_xh(const float* __restrict__ x,
                                            unsigned* __restrict__ A1u,
                                            unsigned* __restrict__ x8u,
                                            const int* __restrict__ dst,
                                            unsigned* __restrict__ gh,
                                            const float* __restrict__ W1l,
                                            const float* __restrict__ W1r,
                                            const float* __restrict__ W2l,
                                            const float* __restrict__ W2r,
                                            unsigned short* __restrict__ Bwt1,
                                            unsigned short* __restrict__ Bwt2){
  int bid = blockIdx.x;
  if (bid < NBBLK){
    __shared__ unsigned h[NBUCK];
    for (int t = threadIdx.x; t < NBUCK; t += 256) h[t] = 0;
    __syncthreads();
    int base = bid * CHUNK;
    for (int j = threadIdx.x; j < CHUNK; j += 256)
      atomicAdd(&h[dst[base + j] >> 9], 1u);
    __syncthreads();
    for (int t = threadIdx.x; t < NBUCK; t += 256) gh[bid * NBUCK + t] = h[t];
    return;
  }
  if (bid < NBBLK + XB){
    int i = (bid - NBBLK) * 256 + threadIdx.x;   // over N*32 float4s
    if (i >= NNODE * 32) return;
    float4 v = ((const float4*)x)[i];
    int e = i * 4;
    int row = e >> 7, c = e & 127;
    unsigned* d = A1u + (size_t)row * 128 + 64 + (c >> 1);
    d[0] = pk2(v.x, v.y);
    d[1] = pk2(v.z, v.w);
    unsigned p = (unsigned)__builtin_amdgcn_cvt_pk_fp8_f32(v.x, v.y, 0, false);
    p = (unsigned)__builtin_amdgcn_cvt_pk_fp8_f32(v.z, v.w, (int)p, true);
    x8u[(size_t)row * 32 + (c >> 2)] = p;
    return;
  }
  int i = (bid - NBBLK - XB) * 256 + threadIdx.x;
  if (i < 256 * 256){
    int n = i >> 8, k = i & 255;
    float v = (k < 128) ? W1l[n * 128 + k] : W1r[n * 128 + (k - 128)];
    Bwt1[i] = f2bf(v);
  } else if (i < 256 * 256 + 128 * 256){
    int i2 = i - 256 * 256;
    int n = i2 >> 8, k = i2 & 255;
    float v = (n < 64) ? W2l[n * 256 + k] : W2r[(n - 64) * 256 + k];
    Bwt2[i2] = f2bf(v);
  }
}

// ---------------- per-bucket scan across the 512 chunks ----------------
__global__ __launch_bounds__(512) void k_scan512(const unsigned* __restrict__ gh,
                                                 unsigned* __restrict__ gbase,
                                                 unsigned* __restrict__ btot){
  int b = blockIdx.x, t = threadIdx.x;
  int lane = t & 63, wv = t >> 6;
  unsigned v = gh[t * NBUCK + b];
  unsigned s = v;
  #pragma unroll
  for (int off = 1; off < 64; off <<= 1){
    unsigned u = __shfl_up(s, off, 64);
    if (lane >= off) s += u;
  }
  __shared__ unsigned wsum[8];
  if (lane == 63) wsum[wv] = s;
  __syncthreads();
  unsigned woff = 0;
  for (int w = 0; w < wv; ++w) woff += wsum[w];
  gbase[t * NBUCK + b] = woff + s - v;
  if (t == 511) btot[b] = woff + s;
}

// ---------------- place edges into bucket-contiguous pairs (local btot scan) ----------------
__global__ __launch_bounds__(256) void k_binscat(const int* __restrict__ src,
                                                 const int* __restrict__ dst,
                                                 const unsigned* __restrict__ gbase,
                                                 const unsigned* __restrict__ btot,
                                                 unsigned* __restrict__ pairs){
  __shared__ unsigned sb[256];
  __shared__ unsigned cur[NBUCK];
  int t = threadIdx.x;
  unsigned v = (t < NBUCK) ? btot[t] : 0u;
  sb[t] = v;
  __syncthreads();
  #pragma unroll
  for (int off = 1; off < 256; off <<= 1){
    unsigned u = (t >= off) ? sb[t - off] : 0u;
    __syncthreads();
    sb[t] += u;
    __syncthreads();
  }
  if (t < NBUCK) cur[t] = (sb[t] - v) + gbase[blockIdx.x * NBUCK + t];
  __syncthreads();
  int base = blockIdx.x * CHUNK;
  for (int j = t; j < CHUNK; j += 256){
    int s = src[base + j], d = dst[base + j];
    unsigned p = atomicAdd(&cur[d >> 9], 1u);
    pairs[p] = ((unsigned)s << 9) | (unsigned)(d & 511);
  }
}

// ---------------- per-bucket node histogram + scan -> rowptr + col ----------------
__global__ __launch_bounds__(512) void k_buildcsr(const unsigned* __restrict__ btot,
                                                  const unsigned* __restrict__ pairs,
                                                  unsigned* __restrict__ rowptr,
                                                  unsigned* __restrict__ col){
  __shared__ unsigned sb[256];
  __shared__ unsigned hist[512];
  __shared__ unsigned wsum[8];
  __shared__ unsigned se0, se1;
  const int b = blockIdx.x, tid = threadIdx.x;
  const int lane = tid & 63, wv = tid >> 6;
  // local exclusive scan of btot to get this bucket's edge range
  if (tid < 256){
    unsigned v = (tid < NBUCK) ? btot[tid] : 0u;
    sb[tid] = v;
  }
  __syncthreads();
  #pragma unroll
  for (int off = 1; off < 256; off <<= 1){
    unsigned u = 0;
    if (tid < 256 && tid >= off) u = sb[tid - off];
    __syncthreads();
    if (tid < 256) sb[tid] += u;
    __syncthreads();
  }
  if (tid == 0){
    se1 = sb[b];
    se0 = sb[b] - btot[b];
    if (b == 0) rowptr[NNODE] = NEDGE;
  }
  hist[tid] = 0;
  __syncthreads();
  const unsigned e0 = se0, e1 = se1;
  const int nb0 = b << 9;
  for (unsigned j = e0 + tid; j < e1; j += 512)
    atomicAdd(&hist[pairs[j] & 511u], 1u);
  __syncthreads();
  unsigned v = hist[tid];
  unsigned s = v;
  #pragma unroll
  for (int off = 1; off < 64; off <<= 1){
    unsigned u = __shfl_up(s, off, 64);
    if (lane >= off) s += u;
  }
  if (lane == 63) wsum[wv] = s;
  __syncthreads();
  unsigned woff = 0;
  for (int w = 0; w < wv; ++w) woff += wsum[w];
  unsigned gpos = e0 + woff + s - v;
  if (nb0 + tid < NNODE) rowptr[nb0 + tid] = gpos;
  __syncthreads();
  hist[tid] = gpos;
  __syncthreads();
  for (unsigned j = e0 + tid; j < e1; j += 512){
    unsigned e = pairs[j];
    unsigned p = atomicAdd(&hist[e & 511u], 1u);
    col[p] = e >> 9;
  }
}

// ---------------- layer-1 aggregation: 16-lane groups, 4 gathers in flight ----------------
__global__ __launch_bounds__(256) void k_agg1(const unsigned* __restrict__ rowptr,
                                              const unsigned* __restrict__ col,
                                              const unsigned* __restrict__ x8u,
                                              unsigned* __restrict__ A1u){
  int gw = (blockIdx.x * 256 + threadIdx.x) >> 6;
  int lane = threadIdx.x & 63;
  if (gw >= NNODE) return;
  unsigned s0 = rowptr[gw], s1 = rowptr[gw + 1];
  const int sel = lane >> 4, u = lane & 15;
  const uint2* x82 = (const uint2*)x8u;   // 16 uint2 per row
  float a0=0.f,a1=0.f,a2=0.f,a3=0.f,a4=0.f,a5=0.f,a6=0.f,a7=0.f;
  f32x2 p;
  unsigned j = s0;
  for (; j + 15 < s1; j += 16){
    unsigned ca = col[j + sel], cb = col[j + 4 + sel];
    unsigned cc = col[j + 8 + sel], cd = col[j + 12 + sel];
    uint2 va = x82[(size_t)ca * 16 + u];
    uint2 vb = x82[(size_t)cb * 16 + u];
    uint2 vc = x82[(size_t)cc * 16 + u];
    uint2 vd = x82[(size_t)cd * 16 + u];
    p = __builtin_amdgcn_cvt_pk_f32_fp8((int)va.x, false); a0+=p.x; a1+=p.y;
    p = __builtin_amdgcn_cvt_pk_f32_fp8((int)va.x, true ); a2+=p.x; a3+=p.y;
    p = __builtin_amdgcn_cvt_pk_f32_fp8((int)va.y, false); a4+=p.x; a5+=p.y;
    p = __builtin_amdgcn_cvt_pk_f32_fp8((int)va.y, true ); a6+=p.x; a7+=p.y;
    p = __builtin_amdgcn_cvt_pk_f32_fp8((int)vb.x, false); a0+=p.x; a1+=p.y;
    p = __builtin_amdgcn_cvt_pk_f32_fp8((int)vb.x, true ); a2+=p.x; a3+=p.y;
    p = __builtin_amdgcn_cvt_pk_f32_fp8((int)vb.y, false); a4+=p.x; a5+=p.y;
    p = __builtin_amdgcn_cvt_pk_f32_fp8((int)vb.y, true ); a6+=p.x; a7+=p.y;
    p = __builtin_amdgcn_cvt_pk_f32_fp8((int)vc.x, false); a0+=p.x; a1+=p.y;
    p = __builtin_amdgcn_cvt_pk_f32_fp8((int)vc.x, true ); a2+=p.x; a3+=p.y;
    p = __builtin_amdgcn_cvt_pk_f32_fp8((int)vc.y, false); a4+=p.x; a5+=p.y;
    p = __builtin_amdgcn_cvt_pk_f32_fp8((int)vc.y, true ); a6+=p.x; a7+=p.y;
    p = __builtin_amdgcn_cvt_pk_f32_fp8((int)vd.x, false); a0+=p.x; a1+=p.y;
    p = __builtin_amdgcn_cvt_pk_f32_fp8((int)vd.x, true ); a2+=p.x; a3+=p.y;
    p = __builtin_amdgcn_cvt_pk_f32_fp8((int)vd.y, false); a4+=p.x; a5+=p.y;
    p = __builtin_amdgcn_cvt_pk_f32_fp8((int)vd.y, true ); a6+=p.x; a7+=p.y;
  }
  for (; j + 3 < s1; j += 4){
    unsigned ca = col[j + sel];
    uint2 va = x82[(size_t)ca * 16 + u];
    p = __builtin_amdgcn_cvt_pk_f32_fp8((int)va.x, false); a0+=p.x; a1+=p.y;
    p = __builtin_amdgcn_cvt_pk_f32_fp8((int)va.x, true ); a2+=p.x; a3+=p.y;
    p = __builtin_amdgcn_cvt_pk_f32_fp8((int)va.y, false); a4+=p.x; a5+=p.y;
    p = __builtin_amdgcn_cvt_pk_f32_fp8((int)va.y, true ); a6+=p.x; a7+=p.y;
  }
  int rem = (int)(s1 - j);
  if (sel < rem){
    unsigned ca = col[j + sel];
    uint2 va = x82[(size_t)ca * 16 + u];
    p = __builtin_amdgcn_cvt_pk_f32_fp8((int)va.x, false); a0+=p.x; a1+=p.y;
    p = __builtin_amdgcn_cvt_pk_f32_fp8((int)va.x, true ); a2+=p.x; a3+=p.y;
    p = __builtin_amdgcn_cvt_pk_f32_fp8((int)va.y, false); a4+=p.x; a5+=p.y;
    p = __builtin_amdgcn_cvt_pk_f32_fp8((int)va.y, true ); a6+=p.x; a7+=p.y;
  }
  a0 += __shfl_xor(a0, 16, 64); a1 += __shfl_xor(a1, 16, 64);
  a2 += __shfl_xor(a2, 16, 64); a3 += __shfl_xor(a3, 16, 64);
  a4 += __shfl_xor(a4, 16, 64); a5 += __shfl_xor(a5, 16, 64);
  a6 += __shfl_xor(a6, 16, 64); a7 += __shfl_xor(a7, 16, 64);
  a0 += __shfl_xor(a0, 32, 64); a1 += __shfl_xor(a1, 32, 64);
  a2 += __shfl_xor(a2, 32, 64); a3 += __shfl_xor(a3, 32, 64);
  a4 += __shfl_xor(a4, 32, 64); a5 += __shfl_xor(a5, 32, 64);
  a6 += __shfl_xor(a6, 32, 64); a7 += __shfl_xor(a7, 32, 64);
  if (lane < 16){
    float inv = 1.f / fmaxf((float)(s1 - s0), 1.f);
    uint4 w;
    w.x = pk2(a0 * inv, a1 * inv);
    w.y = pk2(a2 * inv, a3 * inv);
    w.z = pk2(a4 * inv, a5 * inv);
    w.w = pk2(a6 * inv, a7 * inv);
    *(uint4*)(A1u + (size_t)gw * 128 + 4 * lane) = w;
  }
}

// ---------------- MFMA GEMM, BM=128, 512 threads (2 row-groups x 4 col-groups) ----------------
// MODE 0: bf16 C ; MODE 2: z8 (fp8) + r16 (bf16) split
template<int BN, bool RELU, bool BIAS, int MODE>
__global__ __launch_bounds__(512) void k_gemm(const unsigned short* __restrict__ A,
                                              const unsigned short* __restrict__ B,
                                              const float* __restrict__ bias,
                                              unsigned short* __restrict__ C,
                                              unsigned char* __restrict__ z8,
                                              unsigned short* __restrict__ r16,
                                              int nrows){
  constexpr int NF = BN / 64;              // 16-wide col-frags per wave
  __shared__ unsigned short a_t[128 * 64];
  __shared__ unsigned short b_t[BN * 64];
  const int tid = threadIdx.x, wave = tid >> 6, lane = tid & 63;
  const int wr = wave >> 2, wc = wave & 3;
  const int row0 = blockIdx.x * 128;
  char* ab = (char*)a_t;
  char* bb = (char*)b_t;

  f32x4 acc[4][NF];
  #pragma unroll
  for (int m = 0; m < 4; ++m)
    #pragma unroll
    for (int n = 0; n < NF; ++n)
      acc[m][n] = (f32x4){0.f, 0.f, 0.f, 0.f};

  for (int kt = 0; kt < 4; ++kt){
    { // stage A tile: 128 rows x 64 k ; 512 threads x 2 uint4
      int r = tid >> 2;
      int gr = row0 + r; if (gr > nrows - 1) gr = nrows - 1;
      const uint4* s4 = (const uint4*)(A + (size_t)gr * 256 + kt * 64);
      int c0 = (tid & 3) * 2;
      uint4 v0 = s4[c0], v1 = s4[c0 + 1];
      *(uint4*)(ab + r * 128 + ((c0 * 16) ^ ((r & 7) << 4))) = v0;
      *(uint4*)(ab + r * 128 + (((c0 + 1) * 16) ^ ((r & 7) << 4))) = v1;
    }
    { // stage B tile: BN n-rows x 64 k ; 512 threads x CPT uint4
      constexpr int CPT = BN / 64;
      #pragma unroll
      for (int c = 0; c < CPT; ++c){
        int gc = tid * CPT + c;
        int n = gc >> 3, ck = gc & 7;
        uint4 v = ((const uint4*)(B + (size_t)n * 256 + kt * 64))[ck];
        *(uint4*)(bb + n * 128 + ((ck * 16) ^ ((n & 7) << 4))) = v;
      }
    }
    __syncthreads();
    #pragma unroll
    for (int kk = 0; kk < 2; ++kk){
      int k2 = (kk * 32 + ((lane >> 4) * 8)) * 2;
      bf16x8 af[4];
      #pragma unroll
      for (int m = 0; m < 4; ++m){
        int rr = wr * 64 + m * 16 + (lane & 15);
        af[m] = *(const bf16x8*)(ab + rr * 128 + (k2 ^ ((rr & 7) << 4)));
      }
      #pragma unroll
      for (int n = 0; n < NF; ++n){
        int cc = wc * (16 * NF) + n * 16 + (lane & 15);
        bf16x8 bfv = *(const bf16x8*)(bb + cc * 128 + (k2 ^ ((cc & 7) << 4)));
        #pragma unroll
        for (int m = 0; m < 4; ++m)
          acc[m][n] = __builtin_amdgcn_mfma_f32_16x16x32_bf16(af[m], bfv, acc[m][n], 0, 0, 0);
      }
    }
    __syncthreads();
  }
  #pragma unroll
  for (int m = 0; m < 4; ++m){
    int rbase = row0 + wr * 64 + m * 16 + ((lane >> 4) << 2);
    #pragma unroll
    for (int r = 0; r < 4; ++r){
      if (rbase + r < nrows){
        #pragma unroll
        for (int n = 0; n < NF; ++n){
          int cc = wc * (16 * NF) + n * 16 + (lane & 15);
          float v = acc[m][n][r];
          if (BIAS) v += bias[cc];
          if (RELU) v = fmaxf(v, 0.f);
          if (MODE == 0){
            C[(size_t)(rbase + r) * BN + cc] = f2bf(v);
          } else {
            if (cc < 64)
              z8[(size_t)(rbase + r) * 64 + cc] =
                (unsigned char)__builtin_amdgcn_cvt_pk_fp8_f32(v, v, 0, false);
            else
              r16[(size_t)(rbase + r) * 64 + (cc - 64)] = f2bf(v);
          }
        }
      }
    }
  }
}

// ---------------- layer-2 aggregation: 16-lane groups, 4 gathers in flight ----------------
__global__ __launch_bounds__(256) void k_agg2(const unsigned* __restrict__ rowptr,
                                              const unsigned* __restrict__ col,
                                              const unsigned* __restrict__ z8u,
                                              const unsigned* __restrict__ r16u,
                                              const float* __restrict__ b2,
                                              float* __restrict__ out){
  int gw = (blockIdx.x * 256 + threadIdx.x) >> 6;
  int lane = threadIdx.x & 63;
  if (gw >= NNODE) return;
  unsigned s0 = rowptr[gw], s1 = rowptr[gw + 1];
  const int sel = lane >> 4, u = lane & 15;
  float a0=0.f,a1=0.f,a2=0.f,a3=0.f;
  f32x2 p;
  unsigned j = s0;
  for (; j + 15 < s1; j += 16){
    unsigned ca = col[j + sel], cb = col[j + 4 + sel];
    unsigned cc = col[j + 8 + sel], cd = col[j + 12 + sel];
    unsigned va = z8u[(size_t)ca * 16 + u];
    unsigned vb = z8u[(size_t)cb * 16 + u];
    unsigned vc = z8u[(size_t)cc * 16 + u];
    unsigned vd = z8u[(size_t)cd * 16 + u];
    p = __builtin_amdgcn_cvt_pk_f32_fp8((int)va, false); a0+=p.x; a1+=p.y;
    p = __builtin_amdgcn_cvt_pk_f32_fp8((int)va, true ); a2+=p.x; a3+=p.y;
    p = __builtin_amdgcn_cvt_pk_f32_fp8((int)vb, false); a0+=p.x; a1+=p.y;
    p = __builtin_amdgcn_cvt_pk_f32_fp8((int)vb, true ); a2+=p.x; a3+=p.y;
    p = __builtin_amdgcn_cvt_pk_f32_fp8((int)vc, false); a0+=p.x; a1+=p.y;
    p = __builtin_amdgcn_cvt_pk_f32_fp8((int)vc, true ); a2+=p.x; a3+=p.y;
    p = __builtin_amdgcn_cvt_pk_f32_fp8((int)vd, false); a0+=p.x; a1+=p.y;
    p = __builtin_amdgcn_cvt_pk_f32_fp8((int)vd, true ); a2+=p.x; a3+=p.y;
  }
  for (; j + 3 < s1; j += 4){
    unsigned ca = col[j + sel];
    unsigned va = z8u[(size_t)ca * 16 + u];
    p = __builtin_amdgcn_cvt_pk_f32_fp8((int)va, false); a0+=p.x; a1+=p.y;
    p = __builtin_amdgcn_cvt_pk_f32_fp8((int)va, true ); a2+=p.x; a3+=p.y;
  }
  int rem = (int)(s1 - j);
  if (sel < rem){
    unsigned ca = col[j + sel];
    unsigned va = z8u[(size_t)ca * 16 + u];
    p = __builtin_amdgcn_cvt_pk_f32_fp8((int)va, false); a0+=p.x; a1+=p.y;
    p = __builtin_amdgcn_cvt_pk_f32_fp8((int)va, true ); a2+=p.x; a3+=p.y;
  }
  a0 += __shfl_xor(a0, 16, 64); a1 += __shfl_xor(a1, 16, 64);
  a2 += __shfl_xor(a2, 16, 64); a3 += __shfl_xor(a3, 16, 64);
  a0 += __shfl_xor(a0, 32, 64); a1 += __shfl_xor(a1, 32, 64);
  a2 += __shfl_xor(a2, 32, 64); a3 += __shfl_xor(a3, 32, 64);
  if (lane < 16){
    float inv = 1.f / fmaxf((float)(s1 - s0), 1.f);
    uint2 rv = ((const uint2*)(r16u + (size_t)gw * 32))[lane];
    float4 bv = ((const float4*)b2)[lane];
    float4 res;
    res.x = a0 * inv + bflo(rv.x) + bv.x;
    res.y = a1 * inv + bfhi(rv.x) + bv.y;
    res.z = a2 * inv + bflo(rv.y) + bv.z;
    res.w = a3 * inv + bfhi(rv.y) + bv.w;
    ((float4*)out)[(size_t)gw * 16 + lane] = res;
  }
}

extern "C" void kernel_launch(void* const* d_in, const int* in_sizes, int n_in,
                              void* d_out, int out_size, void* d_ws, size_t ws_size,
                              hipStream_t stream) {
  const float* x   = (const float*)d_in[0];
  const int*   ei  = (const int*)d_in[1];
  const float* W1l = (const float*)d_in[2];
  const float* b1  = (const float*)d_in[3];
  const float* W1r = (const float*)d_in[4];
  const float* W2l = (const float*)d_in[5];
  const float* b2  = (const float*)d_in[6];
  const float* W2r = (const float*)d_in[7];
  float* out = (float*)d_out;

  char* ws = (char*)d_ws;
  size_t off = 0;
  auto alloc = [&](size_t bytes) -> void* {
    void* p = ws + off;
    off = (off + bytes + 255) & ~(size_t)255;
    return p;
  };
  unsigned* rowptr = (unsigned*)alloc((size_t)(NNODE + 1) * 4);
  unsigned* col    = (unsigned*)alloc((size_t)NEDGE * 4);
  unsigned* pairs  = (unsigned*)alloc((size_t)NEDGE * 4);
  unsigned* gh     = (unsigned*)alloc((size_t)NBBLK * NBUCK * 4);
  unsigned* gbase  = (unsigned*)alloc((size_t)NBBLK * NBUCK * 4);
  unsigned* btot   = (unsigned*)alloc((size_t)NBUCK * 4);
  unsigned short* A1   = (unsigned short*)alloc((size_t)NNODE * 256 * 2);
  unsigned short* h    = (unsigned short*)alloc((size_t)NNODE * 256 * 2);
  unsigned short* r16  = (unsigned short*)alloc((size_t)NNODE * 64 * 2);
  unsigned* x8u        = (unsigned*)alloc((size_t)NNODE * 32 * 4);
  unsigned char* z8    = (unsigned char*)alloc((size_t)NNODE * 64);
  unsigned short* Bwt1 = (unsigned short*)alloc(256 * 256 * 2);
  unsigned short* Bwt2 = (unsigned short*)alloc(128 * 256 * 2);

  const int* srcv = ei;
  const int* dstv = ei + NEDGE;

  k_xh<<<NBBLK + XB + WB, 256, 0, stream>>>(x, (unsigned*)A1, x8u, dstv, gh,
                                            W1l, W1r, W2l, W2r, Bwt1, Bwt2);
  k_scan512<<<NBUCK, 512, 0, stream>>>(gh, gbase, btot);
  k_binscat<<<NBBLK, 256, 0, stream>>>(srcv, dstv, gbase, btot, pairs);
  k_buildcsr<<<NBUCK, 512, 0, stream>>>(btot, pairs, rowptr, col);

  k_agg1<<<(NNODE + 3) / 4, 256, 0, stream>>>(rowptr, col, x8u, (unsigned*)A1);

  int gblocks = (NNODE + 127) / 128;
  k_gemm<256, true,  true,  0><<<gblocks, 512, 0, stream>>>(A1, Bwt1, b1, h, nullptr, nullptr, NNODE);
  k_gemm<128, false, false, 2><<<gblocks, 512, 0, stream>>>(h,  Bwt2, nullptr, nullptr, z8, r16, NNODE);

  k_agg2<<<(NNODE + 3) / 4, 256, 0, stream>>>(rowptr, col, (const unsigned*)z8, (const unsigned*)r16, b2, out);
}

// Round 11
// 292.839 us; speedup vs baseline: 1.7773x; 1.0150x over previous
//
#include <hip/hip_runtime.h>
#include <hip/hip_bf16.h>

#define NNODE 100000
#define NEDGE 1600000
#define NBBLK 512
#define CHUNK (NEDGE / NBBLK)              // 3125 edges per binning block
#define NBUCK ((NNODE + 511) >> 9)         // 196 buckets of 512 dst-nodes
#define XB ((NNODE * 32 + 255) / 256)      // 12500 x-convert blocks
#define WB 384                             // weight-convert blocks

typedef __attribute__((ext_vector_type(8))) short bf16x8;
typedef __attribute__((ext_vector_type(4))) float f32x4;
typedef __attribute__((ext_vector_type(2))) float f32x2;

__device__ __forceinline__ unsigned short f2bf(float f){
  unsigned u = __float_as_uint(f);
  u += 0x7fffu + ((u >> 16) & 1u);
  return (unsigned short)(u >> 16);
}
__device__ __forceinline__ unsigned pk2(float a, float b){
  return (unsigned)f2bf(a) | ((unsigned)f2bf(b) << 16);
}
__device__ __forceinline__ float bflo(unsigned v){ return __uint_as_float(v << 16); }
__device__ __forceinline__ float bfhi(unsigned v){ return __uint_as_float(v & 0xffff0000u); }

// ---------------- fused: edge histogram | x conversion | weight conversion ----------------
__global__ __launch_bounds__(256) void k_xh(const float* __restrict__ x,
                                            unsigned* __restrict__ A1u,
                                            unsigned* __restrict__ x8u,
                                            const int* __restrict__ dst,
                                            unsigned* __restrict__ gh,
                                            const float* __restrict__ W1l,
                                            const float* __restrict__ W1r,
                                            const float* __restrict__ W2l,
                                            const float* __restrict__ W2r,
                                            unsigned short* __restrict__ Bwt1,
                                            unsigned short* __restrict__ Bwt2){
  int bid = blockIdx.x;
  if (bid < NBBLK){
    __shared__ unsigned h[NBUCK];
    for (int t = threadIdx.x; t < NBUCK; t += 256) h[t] = 0;
    __syncthreads();
    int base = bid * CHUNK;
    for (int j = threadIdx.x; j < CHUNK; j += 256)
      atomicAdd(&h[dst[base + j] >> 9], 1u);
    __syncthreads();
    for (int t = threadIdx.x; t < NBUCK; t += 256) gh[bid * NBUCK + t] = h[t];
    return;
  }
  if (bid < NBBLK + XB){
    int i = (bid - NBBLK) * 256 + threadIdx.x;   // over N*32 float4s
    if (i >= NNODE * 32) return;
    float4 v = ((const float4*)x)[i];
    int e = i * 4;
    int row = e >> 7, c = e & 127;
    uint2 w;
    w.x = pk2(v.x, v.y);
    w.y = pk2(v.z, v.w);
    *(uint2*)(A1u + (size_t)row * 128 + 64 + (c >> 1)) = w;
    unsigned p = (unsigned)__builtin_amdgcn_cvt_pk_fp8_f32(v.x, v.y, 0, false);
    p = (unsigned)__builtin_amdgcn_cvt_pk_fp8_f32(v.z, v.w, (int)p, true);
    x8u[(size_t)row * 32 + (c >> 2)] = p;
    return;
  }
  int i = (bid - NBBLK - XB) * 256 + threadIdx.x;
  if (i < 256 * 256){
    int n = i >> 8, k = i & 255;
    float v = (k < 128) ? W1l[n * 128 + k] : W1r[n * 128 + (k - 128)];
    Bwt1[i] = f2bf(v);
  } else if (i < 256 * 256 + 128 * 256){
    int i2 = i - 256 * 256;
    int n = i2 >> 8, k = i2 & 255;
    float v = (n < 64) ? W2l[n * 256 + k] : W2r[(n - 64) * 256 + k];
    Bwt2[i2] = f2bf(v);
  }
}

// ---------------- per-bucket scan across the 512 chunks ----------------
__global__ __launch_bounds__(512) void k_scan512(const unsigned* __restrict__ gh,
                                                 unsigned* __restrict__ gbase,
                                                 unsigned* __restrict__ btot){
  int b = blockIdx.x, t = threadIdx.x;
  int lane = t & 63, wv = t >> 6;
  unsigned v = gh[t * NBUCK + b];
  unsigned s = v;
  #pragma unroll
  for (int off = 1; off < 64; off <<= 1){
    unsigned u = __shfl_up(s, off, 64);
    if (lane >= off) s += u;
  }
  __shared__ unsigned wsum[8];
  if (lane == 63) wsum[wv] = s;
  __syncthreads();
  unsigned woff = 0;
  for (int w = 0; w < wv; ++w) woff += wsum[w];
  gbase[t * NBUCK + b] = woff + s - v;
  if (t == 511) btot[b] = woff + s;
}

// ---------------- place edges into bucket-contiguous pairs (local btot scan) ----------------
__global__ __launch_bounds__(256) void k_binscat(const int* __restrict__ src,
                                                 const int* __restrict__ dst,
                                                 const unsigned* __restrict__ gbase,
                                                 const unsigned* __restrict__ btot,
                                                 unsigned* __restrict__ pairs){
  __shared__ unsigned sb[256];
  __shared__ unsigned cur[NBUCK];
  int t = threadIdx.x;
  unsigned v = (t < NBUCK) ? btot[t] : 0u;
  sb[t] = v;
  __syncthreads();
  #pragma unroll
  for (int off = 1; off < 256; off <<= 1){
    unsigned u = (t >= off) ? sb[t - off] : 0u;
    __syncthreads();
    sb[t] += u;
    __syncthreads();
  }
  if (t < NBUCK) cur[t] = (sb[t] - v) + gbase[blockIdx.x * NBUCK + t];
  __syncthreads();
  int base = blockIdx.x * CHUNK;
  for (int j = t; j < CHUNK; j += 256){
    int s = src[base + j], d = dst[base + j];
    unsigned p = atomicAdd(&cur[d >> 9], 1u);
    pairs[p] = ((unsigned)s << 9) | (unsigned)(d & 511);
  }
}

// ---------------- per-bucket node histogram + scan -> rowptr + col ----------------
__global__ __launch_bounds__(512) void k_buildcsr(const unsigned* __restrict__ btot,
                                                  const unsigned* __restrict__ pairs,
                                                  unsigned* __restrict__ rowptr,
                                                  unsigned* __restrict__ col){
  __shared__ unsigned sb[256];
  __shared__ unsigned hist[512];
  __shared__ unsigned wsum[8];
  __shared__ unsigned se0, se1;
  const int b = blockIdx.x, tid = threadIdx.x;
  const int lane = tid & 63, wv = tid >> 6;
  if (tid < 256){
    unsigned v = (tid < NBUCK) ? btot[tid] : 0u;
    sb[tid] = v;
  }
  __syncthreads();
  #pragma unroll
  for (int off = 1; off < 256; off <<= 1){
    unsigned u = 0;
    if (tid < 256 && tid >= off) u = sb[tid - off];
    __syncthreads();
    if (tid < 256) sb[tid] += u;
    __syncthreads();
  }
  if (tid == 0){
    se1 = sb[b];
    se0 = sb[b] - btot[b];
    if (b == 0) rowptr[NNODE] = NEDGE;
  }
  hist[tid] = 0;
  __syncthreads();
  const unsigned e0 = se0, e1 = se1;
  const int nb0 = b << 9;
  for (unsigned j = e0 + tid; j < e1; j += 512)
    atomicAdd(&hist[pairs[j] & 511u], 1u);
  __syncthreads();
  unsigned v = hist[tid];
  unsigned s = v;
  #pragma unroll
  for (int off = 1; off < 64; off <<= 1){
    unsigned u = __shfl_up(s, off, 64);
    if (lane >= off) s += u;
  }
  if (lane == 63) wsum[wv] = s;
  __syncthreads();
  unsigned woff = 0;
  for (int w = 0; w < wv; ++w) woff += wsum[w];
  unsigned gpos = e0 + woff + s - v;
  if (nb0 + tid < NNODE) rowptr[nb0 + tid] = gpos;
  __syncthreads();
  hist[tid] = gpos;
  __syncthreads();
  for (unsigned j = e0 + tid; j < e1; j += 512){
    unsigned e = pairs[j];
    unsigned p = atomicAdd(&hist[e & 511u], 1u);
    col[p] = e >> 9;
  }
}

// ---------------- layer-1 aggregation: 16-lane groups, 4 gathers in flight ----------------
__global__ __launch_bounds__(256) void k_agg1(const unsigned* __restrict__ rowptr,
                                              const unsigned* __restrict__ col,
                                              const unsigned* __restrict__ x8u,
                                              unsigned* __restrict__ A1u){
  int gw = (blockIdx.x * 256 + threadIdx.x) >> 6;
  int lane = threadIdx.x & 63;
  if (gw >= NNODE) return;
  unsigned s0 = rowptr[gw], s1 = rowptr[gw + 1];
  const int sel = lane >> 4, u = lane & 15;
  const uint2* x82 = (const uint2*)x8u;   // 16 uint2 per row
  float a0=0.f,a1=0.f,a2=0.f,a3=0.f,a4=0.f,a5=0.f,a6=0.f,a7=0.f;
  f32x2 p;
  unsigned j = s0;
  for (; j + 15 < s1; j += 16){
    unsigned ca = col[j + sel], cb = col[j + 4 + sel];
    unsigned cc = col[j + 8 + sel], cd = col[j + 12 + sel];
    uint2 va = x82[(size_t)ca * 16 + u];
    uint2 vb = x82[(size_t)cb * 16 + u];
    uint2 vc = x82[(size_t)cc * 16 + u];
    uint2 vd = x82[(size_t)cd * 16 + u];
    p = __builtin_amdgcn_cvt_pk_f32_fp8((int)va.x, false); a0+=p.x; a1+=p.y;
    p = __builtin_amdgcn_cvt_pk_f32_fp8((int)va.x, true ); a2+=p.x; a3+=p.y;
    p = __builtin_amdgcn_cvt_pk_f32_fp8((int)va.y, false); a4+=p.x; a5+=p.y;
    p = __builtin_amdgcn_cvt_pk_f32_fp8((int)va.y, true ); a6+=p.x; a7+=p.y;
    p = __builtin_amdgcn_cvt_pk_f32_fp8((int)vb.x, false); a0+=p.x; a1+=p.y;
    p = __builtin_amdgcn_cvt_pk_f32_fp8((int)vb.x, true ); a2+=p.x; a3+=p.y;
    p = __builtin_amdgcn_cvt_pk_f32_fp8((int)vb.y, false); a4+=p.x; a5+=p.y;
    p = __builtin_amdgcn_cvt_pk_f32_fp8((int)vb.y, true ); a6+=p.x; a7+=p.y;
    p = __builtin_amdgcn_cvt_pk_f32_fp8((int)vc.x, false); a0+=p.x; a1+=p.y;
    p = __builtin_amdgcn_cvt_pk_f32_fp8((int)vc.x, true ); a2+=p.x; a3+=p.y;
    p = __builtin_amdgcn_cvt_pk_f32_fp8((int)vc.y, false); a4+=p.x; a5+=p.y;
    p = __builtin_amdgcn_cvt_pk_f32_fp8((int)vc.y, true ); a6+=p.x; a7+=p.y;
    p = __builtin_amdgcn_cvt_pk_f32_fp8((int)vd.x, false); a0+=p.x; a1+=p.y;
    p = __builtin_amdgcn_cvt_pk_f32_fp8((int)vd.x, true ); a2+=p.x; a3+=p.y;
    p = __builtin_amdgcn_cvt_pk_f32_fp8((int)vd.y, false); a4+=p.x; a5+=p.y;
    p = __builtin_amdgcn_cvt_pk_f32_fp8((int)vd.y, true ); a6+=p.x; a7+=p.y;
  }
  for (; j + 3 < s1; j += 4){
    unsigned ca = col[j + sel];
    uint2 va = x82[(size_t)ca * 16 + u];
    p = __builtin_amdgcn_cvt_pk_f32_fp8((int)va.x, false); a0+=p.x; a1+=p.y;
    p = __builtin_amdgcn_cvt_pk_f32_fp8((int)va.x, true ); a2+=p.x; a3+=p.y;
    p = __builtin_amdgcn_cvt_pk_f32_fp8((int)va.y, false); a4+=p.x; a5+=p.y;
    p = __builtin_amdgcn_cvt_pk_f32_fp8((int)va.y, true ); a6+=p.x; a7+=p.y;
  }
  int rem = (int)(s1 - j);
  if (sel < rem){
    unsigned ca = col[j + sel];
    uint2 va = x82[(size_t)ca * 16 + u];
    p = __builtin_amdgcn_cvt_pk_f32_fp8((int)va.x, false); a0+=p.x; a1+=p.y;
    p = __builtin_amdgcn_cvt_pk_f32_fp8((int)va.x, true ); a2+=p.x; a3+=p.y;
    p = __builtin_amdgcn_cvt_pk_f32_fp8((int)va.y, false); a4+=p.x; a5+=p.y;
    p = __builtin_amdgcn_cvt_pk_f32_fp8((int)va.y, true ); a6+=p.x; a7+=p.y;
  }
  a0 += __shfl_xor(a0, 16, 64); a1 += __shfl_xor(a1, 16, 64);
  a2 += __shfl_xor(a2, 16, 64); a3 += __shfl_xor(a3, 16, 64);
  a4 += __shfl_xor(a4, 16, 64); a5 += __shfl_xor(a5, 16, 64);
  a6 += __shfl_xor(a6, 16, 64); a7 += __shfl_xor(a7, 16, 64);
  a0 += __shfl_xor(a0, 32, 64); a1 += __shfl_xor(a1, 32, 64);
  a2 += __shfl_xor(a2, 32, 64); a3 += __shfl_xor(a3, 32, 64);
  a4 += __shfl_xor(a4, 32, 64); a5 += __shfl_xor(a5, 32, 64);
  a6 += __shfl_xor(a6, 32, 64); a7 += __shfl_xor(a7, 32, 64);
  if (lane < 16){
    float inv = 1.f / fmaxf((float)(s1 - s0), 1.f);
    uint4 w;
    w.x = pk2(a0 * inv, a1 * inv);
    w.y = pk2(a2 * inv, a3 * inv);
    w.z = pk2(a4 * inv, a5 * inv);
    w.w = pk2(a6 * inv, a7 * inv);
    *(uint4*)(A1u + (size_t)gw * 128 + 4 * lane) = w;
  }
}

// ---------------- fused GEMM1+GEMM2: h never leaves the block ----------------
// Phase A: h = relu(A1 @ Bwt1^T + b1) -> acc1 (regs) -> LDS (bf16, per K-half)
// Phase B: [z|r] = h @ Bwt2^T -> z8 (fp8) + r16 (bf16)
__global__ __launch_bounds__(512) void k_gemmf(const unsigned short* __restrict__ A,
                                               const unsigned short* __restrict__ B1,
                                               const float* __restrict__ bias1,
                                               const unsigned short* __restrict__ B2,
                                               unsigned char* __restrict__ z8,
                                               unsigned short* __restrict__ r16,
                                               int nrows){
  __shared__ char smem[65536];
  char* ab  = smem;              // phase A: A tile 128x64 bf16 (16KB)
  char* bb  = smem + 16384;      // phase A: B1 tile 256x64 bf16 (32KB)
  char* hb  = smem;              // phase B: h half-tile 128x128 bf16 (32KB)
  char* bb2 = smem + 32768;      // phase B: B2 half-tile 128x128 bf16 (32KB)
  const int tid = threadIdx.x, wave = tid >> 6, lane = tid & 63;
  const int wr = wave >> 2, wc = wave & 3;
  const int row0 = blockIdx.x * 128;

  f32x4 acc1[4][4];
  #pragma unroll
  for (int m = 0; m < 4; ++m)
    #pragma unroll
    for (int n = 0; n < 4; ++n)
      acc1[m][n] = (f32x4){0.f, 0.f, 0.f, 0.f};

  // ---------- Phase A: gemm1 ----------
  for (int kt = 0; kt < 4; ++kt){
    {
      int r = tid >> 2;
      int gr = row0 + r; if (gr > nrows - 1) gr = nrows - 1;
      const uint4* s4 = (const uint4*)(A + (size_t)gr * 256 + kt * 64);
      int c0 = (tid & 3) * 2;
      uint4 v0 = s4[c0], v1 = s4[c0 + 1];
      *(uint4*)(ab + r * 128 + ((c0 * 16) ^ ((r & 7) << 4))) = v0;
      *(uint4*)(ab + r * 128 + (((c0 + 1) * 16) ^ ((r & 7) << 4))) = v1;
    }
    {
      #pragma unroll
      for (int c = 0; c < 4; ++c){
        int gc = tid * 4 + c;
        int n = gc >> 3, ck = gc & 7;
        uint4 v = ((const uint4*)(B1 + (size_t)n * 256 + kt * 64))[ck];
        *(uint4*)(bb + n * 128 + ((ck * 16) ^ ((n & 7) << 4))) = v;
      }
    }
    __syncthreads();
    #pragma unroll
    for (int kk = 0; kk < 2; ++kk){
      int k2 = (kk * 32 + ((lane >> 4) * 8)) * 2;
      bf16x8 af[4];
      #pragma unroll
      for (int m = 0; m < 4; ++m){
        int rr = wr * 64 + m * 16 + (lane & 15);
        af[m] = *(const bf16x8*)(ab + rr * 128 + (k2 ^ ((rr & 7) << 4)));
      }
      #pragma unroll
      for (int n = 0; n < 4; ++n){
        int cc = wc * 64 + n * 16 + (lane & 15);
        bf16x8 bfv = *(const bf16x8*)(bb + cc * 128 + (k2 ^ ((cc & 7) << 4)));
        #pragma unroll
        for (int m = 0; m < 4; ++m)
          acc1[m][n] = __builtin_amdgcn_mfma_f32_16x16x32_bf16(af[m], bfv, acc1[m][n], 0, 0, 0);
      }
    }
    __syncthreads();
  }

  // bias for this wave's 4 h-columns
  float bv[4];
  #pragma unroll
  for (int n = 0; n < 4; ++n) bv[n] = bias1[wc * 64 + n * 16 + (lane & 15)];

  // ---------- Phase B: gemm2 over two K-halves ----------
  f32x4 acc2[4][2];
  #pragma unroll
  for (int m = 0; m < 4; ++m)
    #pragma unroll
    for (int n = 0; n < 2; ++n)
      acc2[m][n] = (f32x4){0.f, 0.f, 0.f, 0.f};

  for (int kh = 0; kh < 2; ++kh){
    { // stage B2 half: 128 n-rows x 128 k ; 512 threads x 4 uint4
      #pragma unroll
      for (int c = 0; c < 4; ++c){
        int gc = tid * 4 + c;
        int n = gc >> 4, ck = gc & 15;
        uint4 v = ((const uint4*)(B2 + (size_t)n * 256 + kh * 128))[ck];
        *(uint4*)(bb2 + n * 256 + ((ck * 16) ^ ((n & 7) << 4)));
        *(uint4*)(bb2 + n * 256 + ((ck * 16) ^ ((n & 7) << 4))) = v;
      }
    }
    // waves owning this K-half's h columns write them (bias+relu, bf16, swizzled)
    if ((wc >> 1) == kh){
      #pragma unroll
      for (int m = 0; m < 4; ++m){
        int row = wr * 64 + m * 16 + ((lane >> 4) << 2);
        #pragma unroll
        for (int r = 0; r < 4; ++r){
          int rw = row + r;
          #pragma unroll
          for (int n = 0; n < 4; ++n){
            int cl = (wc & 1) * 64 + n * 16 + (lane & 15);   // col within K-half
            float v = fmaxf(acc1[m][n][r] + bv[n], 0.f);
            int byte = rw * 256 + (((cl >> 3) * 16) ^ ((rw & 7) << 4)) + (cl & 7) * 2;
            *(unsigned short*)(hb + byte) = f2bf(v);
          }
        }
      }
    }
    __syncthreads();
    #pragma unroll
    for (int kk = 0; kk < 4; ++kk){
      int k2 = (kk * 32 + ((lane >> 4) * 8)) * 2;
      bf16x8 af[4];
      #pragma unroll
      for (int m = 0; m < 4; ++m){
        int rr = wr * 64 + m * 16 + (lane & 15);
        af[m] = *(const bf16x8*)(hb + rr * 256 + (k2 ^ ((rr & 7) << 4)));
      }
      #pragma unroll
      for (int n = 0; n < 2; ++n){
        int cc = wc * 32 + n * 16 + (lane & 15);
        bf16x8 bfv = *(const bf16x8*)(bb2 + cc * 256 + (k2 ^ ((cc & 7) << 4)));
        #pragma unroll
        for (int m = 0; m < 4; ++m)
          acc2[m][n] = __builtin_amdgcn_mfma_f32_16x16x32_bf16(af[m], bfv, acc2[m][n], 0, 0, 0);
      }
    }
    __syncthreads();
  }

  // ---------- epilogue: z8 (cols 0..63 fp8) + r16 (cols 64..127 bf16) ----------
  #pragma unroll
  for (int m = 0; m < 4; ++m){
    int rbase = row0 + wr * 64 + m * 16 + ((lane >> 4) << 2);
    #pragma unroll
    for (int r = 0; r < 4; ++r){
      if (rbase + r < nrows){
        #pragma unroll
        for (int n = 0; n < 2; ++n){
          int cc = wc * 32 + n * 16 + (lane & 15);
          float v = acc2[m][n][r];
          if (cc < 64)
            z8[(size_t)(rbase + r) * 64 + cc] =
              (unsigned char)__builtin_amdgcn_cvt_pk_fp8_f32(v, v, 0, false);
          else
            r16[(size_t)(rbase + r) * 64 + (cc - 64)] = f2bf(v);
        }
      }
    }
  }
}

// ---------------- layer-2 aggregation: 16-lane groups, 4 gathers in flight ----------------
__global__ __launch_bounds__(256) void k_agg2(const unsigned* __restrict__ rowptr,
                                              const unsigned* __restrict__ col,
                                              const unsigned* __restrict__ z8u,
                                              const unsigned* __restrict__ r16u,
                                              const float* __restrict__ b2,
                                              float* __restrict__ out){
  int gw = (blockIdx.x * 256 + threadIdx.x) >> 6;
  int lane = threadIdx.x & 63;
  if (gw >= NNODE) return;
  unsigned s0 = rowptr[gw], s1 = rowptr[gw + 1];
  const int sel = lane >> 4, u = lane & 15;
  float a0=0.f,a1=0.f,a2=0.f,a3=0.f;
  f32x2 p;
  unsigned j = s0;
  for (; j + 15 < s1; j += 16){
    unsigned ca = col[j + sel], cb = col[j + 4 + sel];
    unsigned cc = col[j + 8 + sel], cd = col[j + 12 + sel];
    unsigned va = z8u[(size_t)ca * 16 + u];
    unsigned vb = z8u[(size_t)cb * 16 + u];
    unsigned vc = z8u[(size_t)cc * 16 + u];
    unsigned vd = z8u[(size_t)cd * 16 + u];
    p = __builtin_amdgcn_cvt_pk_f32_fp8((int)va, false); a0+=p.x; a1+=p.y;
    p = __builtin_amdgcn_cvt_pk_f32_fp8((int)va, true ); a2+=p.x; a3+=p.y;
    p = __builtin_amdgcn_cvt_pk_f32_fp8((int)vb, false); a0+=p.x; a1+=p.y;
    p = __builtin_amdgcn_cvt_pk_f32_fp8((int)vb, true ); a2+=p.x; a3+=p.y;
    p = __builtin_amdgcn_cvt_pk_f32_fp8((int)vc, false); a0+=p.x; a1+=p.y;
    p = __builtin_amdgcn_cvt_pk_f32_fp8((int)vc, true ); a2+=p.x; a3+=p.y;
    p = __builtin_amdgcn_cvt_pk_f32_fp8((int)vd, false); a0+=p.x; a1+=p.y;
    p = __builtin_amdgcn_cvt_pk_f32_fp8((int)vd, true ); a2+=p.x; a3+=p.y;
  }
  for (; j + 3 < s1; j += 4){
    unsigned ca = col[j + sel];
    unsigned va = z8u[(size_t)ca * 16 + u];
    p = __builtin_amdgcn_cvt_pk_f32_fp8((int)va, false); a0+=p.x; a1+=p.y;
    p = __builtin_amdgcn_cvt_pk_f32_fp8((int)va, true ); a2+=p.x; a3+=p.y;
  }
  int rem = (int)(s1 - j);
  if (sel < rem){
    unsigned ca = col[j + sel];
    unsigned va = z8u[(size_t)ca * 16 + u];
    p = __builtin_amdgcn_cvt_pk_f32_fp8((int)va, false); a0+=p.x; a1+=p.y;
    p = __builtin_amdgcn_cvt_pk_f32_fp8((int)va, true ); a2+=p.x; a3+=p.y;
  }
  a0 += __shfl_xor(a0, 16, 64); a1 += __shfl_xor(a1, 16, 64);
  a2 += __shfl_xor(a2, 16, 64); a3 += __shfl_xor(a3, 16, 64);
  a0 += __shfl_xor(a0, 32, 64); a1 += __shfl_xor(a1, 32, 64);
  a2 += __shfl_xor(a2, 32, 64); a3 += __shfl_xor(a3, 32, 64);
  if (lane < 16){
    float inv = 1.f / fmaxf((float)(s1 - s0), 1.f);
    uint2 rv = ((const uint2*)(r16u + (size_t)gw * 32))[lane];
    float4 bv = ((const float4*)b2)[lane];
    float4 res;
    res.x = a0 * inv + bflo(rv.x) + bv.x;
    res.y = a1 * inv + bfhi(rv.x) + bv.y;
    res.z = a2 * inv + bflo(rv.y) + bv.z;
    res.w = a3 * inv + bfhi(rv.y) + bv.w;
    ((float4*)out)[(size_t)gw * 16 + lane] = res;
  }
}

extern "C" void kernel_launch(void* const* d_in, const int* in_sizes, int n_in,
                              void* d_out, int out_size, void* d_ws, size_t ws_size,
                              hipStream_t stream) {
  const float* x   = (const float*)d_in[0];
  const int*   ei  = (const int*)d_in[1];
  const float* W1l = (const float*)d_in[2];
  const float* b1  = (const float*)d_in[3];
  const float* W1r = (const float*)d_in[4];
  const float* W2l = (const float*)d_in[5];
  const float* b2  = (const float*)d_in[6];
  const float* W2r = (const float*)d_in[7];
  float* out = (float*)d_out;

  char* ws = (char*)d_ws;
  size_t off = 0;
  auto alloc = [&](size_t bytes) -> void* {
    void* p = ws + off;
    off = (off + bytes + 255) & ~(size_t)255;
    return p;
  };
  unsigned* rowptr = (unsigned*)alloc((size_t)(NNODE + 1) * 4);
  unsigned* col    = (unsigned*)alloc((size_t)NEDGE * 4);
  unsigned* pairs  = (unsigned*)alloc((size_t)NEDGE * 4);
  unsigned* gh     = (unsigned*)alloc((size_t)NBBLK * NBUCK * 4);
  unsigned* gbase  = (unsigned*)alloc((size_t)NBBLK * NBUCK * 4);
  unsigned* btot   = (unsigned*)alloc((size_t)NBUCK * 4);
  unsigned short* A1   = (unsigned short*)alloc((size_t)NNODE * 256 * 2);
  unsigned short* r16  = (unsigned short*)alloc((size_t)NNODE * 64 * 2);
  unsigned* x8u        = (unsigned*)alloc((size_t)NNODE * 32 * 4);
  unsigned char* z8    = (unsigned char*)alloc((size_t)NNODE * 64);
  unsigned short* Bwt1 = (unsigned short*)alloc(256 * 256 * 2);
  unsigned short* Bwt2 = (unsigned short*)alloc(128 * 256 * 2);

  const int* srcv = ei;
  const int* dstv = ei + NEDGE;

  k_xh<<<NBBLK + XB + WB, 256, 0, stream>>>(x, (unsigned*)A1, x8u, dstv, gh,
                                            W1l, W1r, W2l, W2r, Bwt1, Bwt2);
  k_scan512<<<NBUCK, 512, 0, stream>>>(gh, gbase, btot);
  k_binscat<<<NBBLK, 256, 0, stream>>>(srcv, dstv, gbase, btot, pairs);
  k_buildcsr<<<NBUCK, 512, 0, stream>>>(btot, pairs, rowptr, col);

  k_agg1<<<(NNODE + 3) / 4, 256, 0, stream>>>(rowptr, col, x8u, (unsigned*)A1);

  int gblocks = (NNODE + 127) / 128;
  k_gemmf<<<gblocks, 512, 0, stream>>>(A1, Bwt1, b1, Bwt2, z8, r16, NNODE);

  k_agg2<<<(NNODE + 3) / 4, 256, 0, stream>>>(rowptr, col, (const unsigned*)z8, (const unsigned*)r16, b2, out);
}

// Round 12
// 290.796 us; speedup vs baseline: 1.7897x; 1.0070x over previous
//
#include <hip/hip_runtime.h>
#include <hip/hip_bf16.h>

#define NNODE 100000
#define NEDGE 1600000
#define NBBLK 512
#define CHUNK (NEDGE / NBBLK)              // 3125 edges per binning block
#define NBUCK ((NNODE + 511) >> 9)         // 196 buckets of 512 dst-nodes
#define XB ((NNODE * 32 + 255) / 256)      // 12500 x-convert blocks
#define WB 384                             // weight-convert blocks

typedef __attribute__((ext_vector_type(8))) short bf16x8;
typedef __attribute__((ext_vector_type(4))) float f32x4;
typedef __attribute__((ext_vector_type(2))) float f32x2;

__device__ __forceinline__ unsigned short f2bf(float f){
  unsigned u = __float_as_uint(f);
  u += 0x7fffu + ((u >> 16) & 1u);
  return (unsigned short)(u >> 16);
}
__device__ __forceinline__ unsigned pk2(float a, float b){
  return (unsigned)f2bf(a) | ((unsigned)f2bf(b) << 16);
}
__device__ __forceinline__ float bflo(unsigned v){ return __uint_as_float(v << 16); }
__device__ __forceinline__ float bfhi(unsigned v){ return __uint_as_float(v & 0xffff0000u); }

// async global->LDS, 16B per lane; LDS dest = wave-uniform base + lane*16 (linear)
__device__ __forceinline__ void gll16(const void* g, void* l){
  __builtin_amdgcn_global_load_lds(
      (const __attribute__((address_space(1))) void*)g,
      (__attribute__((address_space(3))) void*)l, 16, 0, 0);
}

// ---------------- fused: edge histogram | x conversion | weight conversion ----------------
__global__ __launch_bounds__(256) void k_xh(const float* __restrict__ x,
                                            unsigned* __restrict__ A1u,
                                            unsigned* __restrict__ x8u,
                                            const int* __restrict__ dst,
                                            unsigned* __restrict__ gh,
                                            const float* __restrict__ W1l,
                                            const float* __restrict__ W1r,
                                            const float* __restrict__ W2l,
                                            const float* __restrict__ W2r,
                                            unsigned short* __restrict__ Bwt1,
                                            unsigned short* __restrict__ Bwt2){
  int bid = blockIdx.x;
  if (bid < NBBLK){
    __shared__ unsigned h[NBUCK];
    for (int t = threadIdx.x; t < NBUCK; t += 256) h[t] = 0;
    __syncthreads();
    int base = bid * CHUNK;
    for (int j = threadIdx.x; j < CHUNK; j += 256)
      atomicAdd(&h[dst[base + j] >> 9], 1u);
    __syncthreads();
    for (int t = threadIdx.x; t < NBUCK; t += 256) gh[bid * NBUCK + t] = h[t];
    return;
  }
  if (bid < NBBLK + XB){
    int i = (bid - NBBLK) * 256 + threadIdx.x;   // over N*32 float4s
    if (i >= NNODE * 32) return;
    float4 v = ((const float4*)x)[i];
    int e = i * 4;
    int row = e >> 7, c = e & 127;
    uint2 w;
    w.x = pk2(v.x, v.y);
    w.y = pk2(v.z, v.w);
    *(uint2*)(A1u + (size_t)row * 128 + 64 + (c >> 1)) = w;
    unsigned p = (unsigned)__builtin_amdgcn_cvt_pk_fp8_f32(v.x, v.y, 0, false);
    p = (unsigned)__builtin_amdgcn_cvt_pk_fp8_f32(v.z, v.w, (int)p, true);
    x8u[(size_t)row * 32 + (c >> 2)] = p;
    return;
  }
  int i = (bid - NBBLK - XB) * 256 + threadIdx.x;
  if (i < 256 * 256){
    int n = i >> 8, k = i & 255;
    float v = (k < 128) ? W1l[n * 128 + k] : W1r[n * 128 + (k - 128)];
    Bwt1[i] = f2bf(v);
  } else if (i < 256 * 256 + 128 * 256){
    int i2 = i - 256 * 256;
    int n = i2 >> 8, k = i2 & 255;
    float v = (n < 64) ? W2l[n * 256 + k] : W2r[(n - 64) * 256 + k];
    Bwt2[i2] = f2bf(v);
  }
}

// ---------------- per-bucket scan across the 512 chunks ----------------
__global__ __launch_bounds__(512) void k_scan512(const unsigned* __restrict__ gh,
                                                 unsigned* __restrict__ gbase,
                                                 unsigned* __restrict__ btot){
  int b = blockIdx.x, t = threadIdx.x;
  int lane = t & 63, wv = t >> 6;
  unsigned v = gh[t * NBUCK + b];
  unsigned s = v;
  #pragma unroll
  for (int off = 1; off < 64; off <<= 1){
    unsigned u = __shfl_up(s, off, 64);
    if (lane >= off) s += u;
  }
  __shared__ unsigned wsum[8];
  if (lane == 63) wsum[wv] = s;
  __syncthreads();
  unsigned woff = 0;
  for (int w = 0; w < wv; ++w) woff += wsum[w];
  gbase[t * NBUCK + b] = woff + s - v;
  if (t == 511) btot[b] = woff + s;
}

// ---------------- place edges into bucket-contiguous pairs (local btot scan) ----------------
__global__ __launch_bounds__(256) void k_binscat(const int* __restrict__ src,
                                                 const int* __restrict__ dst,
                                                 const unsigned* __restrict__ gbase,
                                                 const unsigned* __restrict__ btot,
                                                 unsigned* __restrict__ pairs){
  __shared__ unsigned sb[256];
  __shared__ unsigned cur[NBUCK];
  int t = threadIdx.x;
  unsigned v = (t < NBUCK) ? btot[t] : 0u;
  sb[t] = v;
  __syncthreads();
  #pragma unroll
  for (int off = 1; off < 256; off <<= 1){
    unsigned u = (t >= off) ? sb[t - off] : 0u;
    __syncthreads();
    sb[t] += u;
    __syncthreads();
  }
  if (t < NBUCK) cur[t] = (sb[t] - v) + gbase[blockIdx.x * NBUCK + t];
  __syncthreads();
  int base = blockIdx.x * CHUNK;
  for (int j = t; j < CHUNK; j += 256){
    int s = src[base + j], d = dst[base + j];
    unsigned p = atomicAdd(&cur[d >> 9], 1u);
    pairs[p] = ((unsigned)s << 9) | (unsigned)(d & 511);
  }
}

// ---------------- per-bucket node histogram + scan -> rowptr + col ----------------
__global__ __launch_bounds__(512) void k_buildcsr(const unsigned* __restrict__ btot,
                                                  const unsigned* __restrict__ pairs,
                                                  unsigned* __restrict__ rowptr,
                                                  unsigned* __restrict__ col){
  __shared__ unsigned sb[256];
  __shared__ unsigned hist[512];
  __shared__ unsigned wsum[8];
  __shared__ unsigned se0, se1;
  const int b = blockIdx.x, tid = threadIdx.x;
  const int lane = tid & 63, wv = tid >> 6;
  if (tid < 256){
    unsigned v = (tid < NBUCK) ? btot[tid] : 0u;
    sb[tid] = v;
  }
  __syncthreads();
  #pragma unroll
  for (int off = 1; off < 256; off <<= 1){
    unsigned u = 0;
    if (tid < 256 && tid >= off) u = sb[tid - off];
    __syncthreads();
    if (tid < 256) sb[tid] += u;
    __syncthreads();
  }
  if (tid == 0){
    se1 = sb[b];
    se0 = sb[b] - btot[b];
    if (b == 0) rowptr[NNODE] = NEDGE;
  }
  hist[tid] = 0;
  __syncthreads();
  const unsigned e0 = se0, e1 = se1;
  const int nb0 = b << 9;
  for (unsigned j = e0 + tid; j < e1; j += 512)
    atomicAdd(&hist[pairs[j] & 511u], 1u);
  __syncthreads();
  unsigned v = hist[tid];
  unsigned s = v;
  #pragma unroll
  for (int off = 1; off < 64; off <<= 1){
    unsigned u = __shfl_up(s, off, 64);
    if (lane >= off) s += u;
  }
  if (lane == 63) wsum[wv] = s;
  __syncthreads();
  unsigned woff = 0;
  for (int w = 0; w < wv; ++w) woff += wsum[w];
  unsigned gpos = e0 + woff + s - v;
  if (nb0 + tid < NNODE) rowptr[nb0 + tid] = gpos;
  __syncthreads();
  hist[tid] = gpos;
  __syncthreads();
  for (unsigned j = e0 + tid; j < e1; j += 512){
    unsigned e = pairs[j];
    unsigned p = atomicAdd(&hist[e & 511u], 1u);
    col[p] = e >> 9;
  }
}

// ---------------- layer-1 aggregation: 16-lane groups, 4 gathers in flight ----------------
__global__ __launch_bounds__(256) void k_agg1(const unsigned* __restrict__ rowptr,
                                              const unsigned* __restrict__ col,
                                              const unsigned* __restrict__ x8u,
                                              unsigned* __restrict__ A1u){
  int gw = (blockIdx.x * 256 + threadIdx.x) >> 6;
  int lane = threadIdx.x & 63;
  if (gw >= NNODE) return;
  unsigned s0 = rowptr[gw], s1 = rowptr[gw + 1];
  const int sel = lane >> 4, u = lane & 15;
  const uint2* x82 = (const uint2*)x8u;   // 16 uint2 per row
  float a0=0.f,a1=0.f,a2=0.f,a3=0.f,a4=0.f,a5=0.f,a6=0.f,a7=0.f;
  f32x2 p;
  unsigned j = s0;
  for (; j + 15 < s1; j += 16){
    unsigned ca = col[j + sel], cb = col[j + 4 + sel];
    unsigned cc = col[j + 8 + sel], cd = col[j + 12 + sel];
    uint2 va = x82[(size_t)ca * 16 + u];
    uint2 vb = x82[(size_t)cb * 16 + u];
    uint2 vc = x82[(size_t)cc * 16 + u];
    uint2 vd = x82[(size_t)cd * 16 + u];
    p = __builtin_amdgcn_cvt_pk_f32_fp8((int)va.x, false); a0+=p.x; a1+=p.y;
    p = __builtin_amdgcn_cvt_pk_f32_fp8((int)va.x, true ); a2+=p.x; a3+=p.y;
    p = __builtin_amdgcn_cvt_pk_f32_fp8((int)va.y, false); a4+=p.x; a5+=p.y;
    p = __builtin_amdgcn_cvt_pk_f32_fp8((int)va.y, true ); a6+=p.x; a7+=p.y;
    p = __builtin_amdgcn_cvt_pk_f32_fp8((int)vb.x, false); a0+=p.x; a1+=p.y;
    p = __builtin_amdgcn_cvt_pk_f32_fp8((int)vb.x, true ); a2+=p.x; a3+=p.y;
    p = __builtin_amdgcn_cvt_pk_f32_fp8((int)vb.y, false); a4+=p.x; a5+=p.y;
    p = __builtin_amdgcn_cvt_pk_f32_fp8((int)vb.y, true ); a6+=p.x; a7+=p.y;
    p = __builtin_amdgcn_cvt_pk_f32_fp8((int)vc.x, false); a0+=p.x; a1+=p.y;
    p = __builtin_amdgcn_cvt_pk_f32_fp8((int)vc.x, true ); a2+=p.x; a3+=p.y;
    p = __builtin_amdgcn_cvt_pk_f32_fp8((int)vc.y, false); a4+=p.x; a5+=p.y;
    p = __builtin_amdgcn_cvt_pk_f32_fp8((int)vc.y, true ); a6+=p.x; a7+=p.y;
    p = __builtin_amdgcn_cvt_pk_f32_fp8((int)vd.x, false); a0+=p.x; a1+=p.y;
    p = __builtin_amdgcn_cvt_pk_f32_fp8((int)vd.x, true ); a2+=p.x; a3+=p.y;
    p = __builtin_amdgcn_cvt_pk_f32_fp8((int)vd.y, false); a4+=p.x; a5+=p.y;
    p = __builtin_amdgcn_cvt_pk_f32_fp8((int)vd.y, true ); a6+=p.x; a7+=p.y;
  }
  for (; j + 3 < s1; j += 4){
    unsigned ca = col[j + sel];
    uint2 va = x82[(size_t)ca * 16 + u];
    p = __builtin_amdgcn_cvt_pk_f32_fp8((int)va.x, false); a0+=p.x; a1+=p.y;
    p = __builtin_amdgcn_cvt_pk_f32_fp8((int)va.x, true ); a2+=p.x; a3+=p.y;
    p = __builtin_amdgcn_cvt_pk_f32_fp8((int)va.y, false); a4+=p.x; a5+=p.y;
    p = __builtin_amdgcn_cvt_pk_f32_fp8((int)va.y, true ); a6+=p.x; a7+=p.y;
  }
  int rem = (int)(s1 - j);
  if (sel < rem){
    unsigned ca = col[j + sel];
    uint2 va = x82[(size_t)ca * 16 + u];
    p = __builtin_amdgcn_cvt_pk_f32_fp8((int)va.x, false); a0+=p.x; a1+=p.y;
    p = __builtin_amdgcn_cvt_pk_f32_fp8((int)va.x, true ); a2+=p.x; a3+=p.y;
    p = __builtin_amdgcn_cvt_pk_f32_fp8((int)va.y, false); a4+=p.x; a5+=p.y;
    p = __builtin_amdgcn_cvt_pk_f32_fp8((int)va.y, true ); a6+=p.x; a7+=p.y;
  }
  a0 += __shfl_xor(a0, 16, 64); a1 += __shfl_xor(a1, 16, 64);
  a2 += __shfl_xor(a2, 16, 64); a3 += __shfl_xor(a3, 16, 64);
  a4 += __shfl_xor(a4, 16, 64); a5 += __shfl_xor(a5, 16, 64);
  a6 += __shfl_xor(a6, 16, 64); a7 += __shfl_xor(a7, 16, 64);
  a0 += __shfl_xor(a0, 32, 64); a1 += __shfl_xor(a1, 32, 64);
  a2 += __shfl_xor(a2, 32, 64); a3 += __shfl_xor(a3, 32, 64);
  a4 += __shfl_xor(a4, 32, 64); a5 += __shfl_xor(a5, 32, 64);
  a6 += __shfl_xor(a6, 32, 64); a7 += __shfl_xor(a7, 32, 64);
  if (lane < 16){
    float inv = 1.f / fmaxf((float)(s1 - s0), 1.f);
    uint4 w;
    w.x = pk2(a0 * inv, a1 * inv);
    w.y = pk2(a2 * inv, a3 * inv);
    w.z = pk2(a4 * inv, a5 * inv);
    w.w = pk2(a6 * inv, a7 * inv);
    *(uint4*)(A1u + (size_t)gw * 128 + 4 * lane) = w;
  }
}

// ---------------- fused GEMM1+GEMM2 with async global_load_lds staging ----------------
// LDS is LINEAR; the bank-swizzle is folded into the per-lane GLOBAL source chunk
// (slot s holds global chunk s^(row&7)); swizzled ds_read_b128 on the consume side.
__global__ __launch_bounds__(512) void k_gemmf(const unsigned short* __restrict__ A,
                                               const unsigned short* __restrict__ B1,
                                               const float* __restrict__ bias1,
                                               const unsigned short* __restrict__ B2,
                                               unsigned char* __restrict__ z8,
                                               unsigned short* __restrict__ r16,
                                               int nrows){
  __shared__ char smem[65536];
  char* ab  = smem;              // phase A: A tile 128x64 bf16 (16KB, 128B rows)
  char* bb  = smem + 16384;      // phase A: B1 tile 256x64 bf16 (32KB, 128B rows)
  char* hb  = smem;              // phase B: h half-tile 128x128 bf16 (32KB, 256B rows)
  char* bb2 = smem + 32768;      // phase B: B2 half-tile 128x128 bf16 (32KB, 256B rows)
  const int tid = threadIdx.x, wave = tid >> 6, lane = tid & 63;
  const int wr = wave >> 2, wc = wave & 3;
  const int row0 = blockIdx.x * 128;

  f32x4 acc1[4][4];
  #pragma unroll
  for (int m = 0; m < 4; ++m)
    #pragma unroll
    for (int n = 0; n < 4; ++n)
      acc1[m][n] = (f32x4){0.f, 0.f, 0.f, 0.f};

  // ---------- Phase A: gemm1 ----------
  for (int kt = 0; kt < 4; ++kt){
    // A tile: 16KB = 16 wave-instr; 2 per wave
    #pragma unroll
    for (int i = 0; i < 2; ++i){
      int q = (wave * 2 + i) * 64 + lane;      // [0,1024)
      int r = q >> 3, s = q & 7;
      int ck = s ^ (r & 7);
      int gr = row0 + r; if (gr > nrows - 1) gr = nrows - 1;
      gll16(A + (size_t)gr * 256 + kt * 64 + ck * 8, ab + (wave * 2 + i) * 1024);
    }
    // B1 tile: 32KB = 32 wave-instr; 4 per wave
    #pragma unroll
    for (int i = 0; i < 4; ++i){
      int q = (wave * 4 + i) * 64 + lane;      // [0,2048)
      int n = q >> 3, s = q & 7;
      int ck = s ^ (n & 7);
      gll16(B1 + (size_t)n * 256 + kt * 64 + ck * 8, bb + (wave * 4 + i) * 1024);
    }
    __syncthreads();
    #pragma unroll
    for (int kk = 0; kk < 2; ++kk){
      int k2 = (kk * 32 + ((lane >> 4) * 8)) * 2;
      bf16x8 af[4];
      #pragma unroll
      for (int m = 0; m < 4; ++m){
        int rr = wr * 64 + m * 16 + (lane & 15);
        af[m] = *(const bf16x8*)(ab + rr * 128 + (k2 ^ ((rr & 7) << 4)));
      }
      #pragma unroll
      for (int n = 0; n < 4; ++n){
        int cc = wc * 64 + n * 16 + (lane & 15);
        bf16x8 bfv = *(const bf16x8*)(bb + cc * 128 + (k2 ^ ((cc & 7) << 4)));
        #pragma unroll
        for (int m = 0; m < 4; ++m)
          acc1[m][n] = __builtin_amdgcn_mfma_f32_16x16x32_bf16(af[m], bfv, acc1[m][n], 0, 0, 0);
      }
    }
    __syncthreads();
  }

  // bias for this wave's 4 h-columns
  float bv[4];
  #pragma unroll
  for (int n = 0; n < 4; ++n) bv[n] = bias1[wc * 64 + n * 16 + (lane & 15)];

  // ---------- Phase B: gemm2 over two K-halves ----------
  f32x4 acc2[4][2];
  #pragma unroll
  for (int m = 0; m < 4; ++m)
    #pragma unroll
    for (int n = 0; n < 2; ++n)
      acc2[m][n] = (f32x4){0.f, 0.f, 0.f, 0.f};

  for (int kh = 0; kh < 2; ++kh){
    // B2 half: 32KB = 32 wave-instr; 4 per wave (rows 256B, 16 slots, XOR low 3 bits)
    #pragma unroll
    for (int i = 0; i < 4; ++i){
      int q = (wave * 4 + i) * 64 + lane;      // [0,2048)
      int n = q >> 4, s = q & 15;
      int ck = s ^ (n & 7);
      gll16(B2 + (size_t)n * 256 + kh * 128 + ck * 8, bb2 + (wave * 4 + i) * 1024);
    }
    // waves owning this K-half's h columns write them (bias+relu, bf16, swizzled)
    if ((wc >> 1) == kh){
      #pragma unroll
      for (int m = 0; m < 4; ++m){
        int row = wr * 64 + m * 16 + ((lane >> 4) << 2);
        #pragma unroll
        for (int r = 0; r < 4; ++r){
          int rw = row + r;
          #pragma unroll
          for (int n = 0; n < 4; ++n){
            int cl = (wc & 1) * 64 + n * 16 + (lane & 15);   // col within K-half
            float v = fmaxf(acc1[m][n][r] + bv[n], 0.f);
            int byte = rw * 256 + (((cl >> 3) * 16) ^ ((rw & 7) << 4)) + (cl & 7) * 2;
            *(unsigned short*)(hb + byte) = f2bf(v);
          }
        }
      }
    }
    __syncthreads();
    #pragma unroll
    for (int kk = 0; kk < 4; ++kk){
      int k2 = (kk * 32 + ((lane >> 4) * 8)) * 2;
      bf16x8 af[4];
      #pragma unroll
      for (int m = 0; m < 4; ++m){
        int rr = wr * 64 + m * 16 + (lane & 15);
        af[m] = *(const bf16x8*)(hb + rr * 256 + (k2 ^ ((rr & 7) << 4)));
      }
      #pragma unroll
      for (int n = 0; n < 2; ++n){
        int cc = wc * 32 + n * 16 + (lane & 15);
        bf16x8 bfv = *(const bf16x8*)(bb2 + cc * 256 + (k2 ^ ((cc & 7) << 4)));
        #pragma unroll
        for (int m = 0; m < 4; ++m)
          acc2[m][n] = __builtin_amdgcn_mfma_f32_16x16x32_bf16(af[m], bfv, acc2[m][n], 0, 0, 0);
      }
    }
    __syncthreads();
  }

  // ---------- epilogue: z8 (cols 0..63 fp8) + r16 (cols 64..127 bf16) ----------
  #pragma unroll
  for (int m = 0; m < 4; ++m){
    int rbase = row0 + wr * 64 + m * 16 + ((lane >> 4) << 2);
    #pragma unroll
    for (int r = 0; r < 4; ++r){
      if (rbase + r < nrows){
        #pragma unroll
        for (int n = 0; n < 2; ++n){
          int cc = wc * 32 + n * 16 + (lane & 15);
          float v = acc2[m][n][r];
          if (cc < 64)
            z8[(size_t)(rbase + r) * 64 + cc] =
              (unsigned char)__builtin_amdgcn_cvt_pk_fp8_f32(v, v, 0, false);
          else
            r16[(size_t)(rbase + r) * 64 + (cc - 64)] = f2bf(v);
        }
      }
    }
  }
}

// ---------------- layer-2 aggregation: 16-lane groups, 4 gathers in flight ----------------
__global__ __launch_bounds__(256) void k_agg2(const unsigned* __restrict__ rowptr,
                                              const unsigned* __restrict__ col,
                                              const unsigned* __restrict__ z8u,
                                              const unsigned* __restrict__ r16u,
                                              const float* __restrict__ b2,
                                              float* __restrict__ out){
  int gw = (blockIdx.x * 256 + threadIdx.x) >> 6;
  int lane = threadIdx.x & 63;
  if (gw >= NNODE) return;
  unsigned s0 = rowptr[gw], s1 = rowptr[gw + 1];
  const int sel = lane >> 4, u = lane & 15;
  float a0=0.f,a1=0.f,a2=0.f,a3=0.f;
  f32x2 p;
  unsigned j = s0;
  for (; j + 15 < s1; j += 16){
    unsigned ca = col[j + sel], cb = col[j + 4 + sel];
    unsigned cc = col[j + 8 + sel], cd = col[j + 12 + sel];
    unsigned va = z8u[(size_t)ca * 16 + u];
    unsigned vb = z8u[(size_t)cb * 16 + u];
    unsigned vc = z8u[(size_t)cc * 16 + u];
    unsigned vd = z8u[(size_t)cd * 16 + u];
    p = __builtin_amdgcn_cvt_pk_f32_fp8((int)va, false); a0+=p.x; a1+=p.y;
    p = __builtin_amdgcn_cvt_pk_f32_fp8((int)va, true ); a2+=p.x; a3+=p.y;
    p = __builtin_amdgcn_cvt_pk_f32_fp8((int)vb, false); a0+=p.x; a1+=p.y;
    p = __builtin_amdgcn_cvt_pk_f32_fp8((int)vb, true ); a2+=p.x; a3+=p.y;
    p = __builtin_amdgcn_cvt_pk_f32_fp8((int)vc, false); a0+=p.x; a1+=p.y;
    p = __builtin_amdgcn_cvt_pk_f32_fp8((int)vc, true ); a2+=p.x; a3+=p.y;
    p = __builtin_amdgcn_cvt_pk_f32_fp8((int)vd, false); a0+=p.x; a1+=p.y;
    p = __builtin_amdgcn_cvt_pk_f32_fp8((int)vd, true ); a2+=p.x; a3+=p.y;
  }
  for (; j + 3 < s1; j += 4){
    unsigned ca = col[j + sel];
    unsigned va = z8u[(size_t)ca * 16 + u];
    p = __builtin_amdgcn_cvt_pk_f32_fp8((int)va, false); a0+=p.x; a1+=p.y;
    p = __builtin_amdgcn_cvt_pk_f32_fp8((int)va, true ); a2+=p.x; a3+=p.y;
  }
  int rem = (int)(s1 - j);
  if (sel < rem){
    unsigned ca = col[j + sel];
    unsigned va = z8u[(size_t)ca * 16 + u];
    p = __builtin_amdgcn_cvt_pk_f32_fp8((int)va, false); a0+=p.x; a1+=p.y;
    p = __builtin_amdgcn_cvt_pk_f32_fp8((int)va, true ); a2+=p.x; a3+=p.y;
  }
  a0 += __shfl_xor(a0, 16, 64); a1 += __shfl_xor(a1, 16, 64);
  a2 += __shfl_xor(a2, 16, 64); a3 += __shfl_xor(a3, 16, 64);
  a0 += __shfl_xor(a0, 32, 64); a1 += __shfl_xor(a1, 32, 64);
  a2 += __shfl_xor(a2, 32, 64); a3 += __shfl_xor(a3, 32, 64);
  if (lane < 16){
    float inv = 1.f / fmaxf((float)(s1 - s0), 1.f);
    uint2 rv = ((const uint2*)(r16u + (size_t)gw * 32))[lane];
    float4 bv = ((const float4*)b2)[lane];
    float4 res;
    res.x = a0 * inv + bflo(rv.x) + bv.x;
    res.y = a1 * inv + bfhi(rv.x) + bv.y;
    res.z = a2 * inv + bflo(rv.y) + bv.z;
    res.w = a3 * inv + bfhi(rv.y) + bv.w;
    ((float4*)out)[(size_t)gw * 16 + lane] = res;
  }
}

extern "C" void kernel_launch(void* const* d_in, const int* in_sizes, int n_in,
                              void* d_out, int out_size, void* d_ws, size_t ws_size,
                              hipStream_t stream) {
  const float* x   = (const float*)d_in[0];
  const int*   ei  = (const int*)d_in[1];
  const float* W1l = (const float*)d_in[2];
  const float* b1  = (const float*)d_in[3];
  const float* W1r = (const float*)d_in[4];
  const float* W2l = (const float*)d_in[5];
  const float* b2  = (const float*)d_in[6];
  const float* W2r = (const float*)d_in[7];
  float* out = (float*)d_out;

  char* ws = (char*)d_ws;
  size_t off = 0;
  auto alloc = [&](size_t bytes) -> void* {
    void* p = ws + off;
    off = (off + bytes + 255) & ~(size_t)255;
    return p;
  };
  unsigned* rowptr = (unsigned*)alloc((size_t)(NNODE + 1) * 4);
  unsigned* col    = (unsigned*)alloc((size_t)NEDGE * 4);
  unsigned* pairs  = (unsigned*)alloc((size_t)NEDGE * 4);
  unsigned* gh     = (unsigned*)alloc((size_t)NBBLK * NBUCK * 4);
  unsigned* gbase  = (unsigned*)alloc((size_t)NBBLK * NBUCK * 4);
  unsigned* btot   = (unsigned*)alloc((size_t)NBUCK * 4);
  unsigned short* A1   = (unsigned short*)alloc((size_t)NNODE * 256 * 2);
  unsigned short* r16  = (unsigned short*)alloc((size_t)NNODE * 64 * 2);
  unsigned* x8u        = (unsigned*)alloc((size_t)NNODE * 32 * 4);
  unsigned char* z8    = (unsigned char*)alloc((size_t)NNODE * 64);
  unsigned short* Bwt1 = (unsigned short*)alloc(256 * 256 * 2);
  unsigned short* Bwt2 = (unsigned short*)alloc(128 * 256 * 2);

  const int* srcv = ei;
  const int* dstv = ei + NEDGE;

  k_xh<<<NBBLK + XB + WB, 256, 0, stream>>>(x, (unsigned*)A1, x8u, dstv, gh,
                                            W1l, W1r, W2l, W2r, Bwt1, Bwt2);
  k_scan512<<<NBUCK, 512, 0, stream>>>(gh, gbase, btot);
  k_binscat<<<NBBLK, 256, 0, stream>>>(srcv, dstv, gbase, btot, pairs);
  k_buildcsr<<<NBUCK, 512, 0, stream>>>(btot, pairs, rowptr, col);

  k_agg1<<<(NNODE + 3) / 4, 256, 0, stream>>>(rowptr, col, x8u, (unsigned*)A1);

  int gblocks = (NNODE + 127) / 128;
  k_gemmf<<<gblocks, 512, 0, stream>>>(A1, Bwt1, b1, Bwt2, z8, r16, NNODE);

  k_agg2<<<(NNODE + 3) / 4, 256, 0, stream>>>(rowptr, col, (const unsigned*)z8, (const unsigned*)r16, b2, out);
}